// Round 3
// baseline (921.931 us; speedup 1.0000x reference)
//
#include <hip/hip_runtime.h>
#include <hip/hip_bf16.h>
#include <stdint.h>

#define DIM 512
#define HEADS 16
#define NTOK 73728
#define INNER 1344
#define INNERP 1408

typedef __attribute__((ext_vector_type(8))) short vbf8;
typedef __attribute__((ext_vector_type(4))) float vf4;

typedef __attribute__((address_space(1))) void as1void;
typedef __attribute__((address_space(3))) void as3void;

__device__ __forceinline__ int imin(int a, int b) { return a < b ? a : b; }

// ---------------- weight transpose + bf16 cast (optionally padded/remapped) ----------------
// WT[n'][k] = W[k][n], n' = n + (n>=nsplit ? 64 : 0)
__global__ void k_transpose(const float* __restrict__ Wsrc, __hip_bfloat16* __restrict__ WT,
                            int K, int N, int ldOut, int nsplit) {
  __shared__ float tile[32][33];
  const int tx = threadIdx.x, ty = threadIdx.y;
  const int n0 = blockIdx.x * 32, k0 = blockIdx.y * 32;
#pragma unroll
  for (int i = 0; i < 32; i += 8) {
    int k = k0 + ty + i, n = n0 + tx;
    if (k < K && n < N) tile[ty + i][tx] = Wsrc[(size_t)k * N + n];
  }
  __syncthreads();
#pragma unroll
  for (int i = 0; i < 32; i += 8) {
    int n = n0 + ty + i, k = k0 + tx;
    if (n < N && k < K) {
      int np = n + (n >= nsplit ? 64 : 0);
      WT[(size_t)np * ldOut + k] = __float2bfloat16(tile[tx][ty + i]);
    }
  }
}

// ---------------- pad GLU bias into [2816]: [0,1344)=b, [1408,2752)=b+1344, pads stay 0 ----
__global__ void k_padbias(const float* __restrict__ b, float* __restrict__ o) {
  int c = blockIdx.x * 256 + threadIdx.x;  // 0..2815
  if (c < INNER) o[c] = b[c];
  else if (c >= INNERP && c < INNERP + INNER) o[c] = b[c - 64];
}

// ---------------- LayerNorm (+ optional window partition), fp32 -> bf16 ----------------
template <bool PART>
__global__ __launch_bounds__(256) void k_ln(const float* __restrict__ x,
                                            const float* __restrict__ gw,
                                            const float* __restrict__ bw,
                                            __hip_bfloat16* __restrict__ y) {
  const int wave = threadIdx.x >> 6, lane = threadIdx.x & 63;
  const int tok = blockIdx.x * 4 + wave;
  const float* xr = x + (size_t)tok * DIM + lane * 8;
  const float4 v0 = *(const float4*)xr;
  const float4 v1 = *(const float4*)(xr + 4);
  float s = v0.x + v0.y + v0.z + v0.w + v1.x + v1.y + v1.z + v1.w;
  float ss = v0.x * v0.x + v0.y * v0.y + v0.z * v0.z + v0.w * v0.w +
             v1.x * v1.x + v1.y * v1.y + v1.z * v1.z + v1.w * v1.w;
#pragma unroll
  for (int off = 32; off > 0; off >>= 1) {
    s += __shfl_xor(s, off);
    ss += __shfl_xor(ss, off);
  }
  const float mu = s * (1.0f / DIM);
  const float rs = rsqrtf(ss * (1.0f / DIM) - mu * mu + 1e-6f);
  size_t orow;
  if (PART) {
    int b = tok / 9216, rem = tok % 9216;
    int h = rem / 96, w = rem % 96;
    orow = (size_t)(((b * 12 + (h >> 3)) * 12 + (w >> 3)) * 64 + (h & 7) * 8 + (w & 7));
  } else {
    orow = (size_t)tok;
  }
  const float4 g0 = *(const float4*)(gw + lane * 8);
  const float4 g1 = *(const float4*)(gw + lane * 8 + 4);
  const float4 b0 = *(const float4*)(bw + lane * 8);
  const float4 b1 = *(const float4*)(bw + lane * 8 + 4);
  const float vals[8] = {v0.x, v0.y, v0.z, v0.w, v1.x, v1.y, v1.z, v1.w};
  const float gg[8] = {g0.x, g0.y, g0.z, g0.w, g1.x, g1.y, g1.z, g1.w};
  const float bb[8] = {b0.x, b0.y, b0.z, b0.w, b1.x, b1.y, b1.z, b1.w};
  union {
    vbf8 v;
    __hip_bfloat16 e[8];
  } po;
#pragma unroll
  for (int j = 0; j < 8; ++j) po.e[j] = __float2bfloat16((vals[j] - mu) * rs * gg[j] + bb[j]);
  *(vbf8*)(y + orow * DIM + lane * 8) = po.v;
}

// =====================================================================================
// 256x256 8-phase GEMM (T1+T2+T3+T4+T5). C = A[M,K] * BT[N,K]^T.
// 8 waves = 2M x 4N, per-wave 128x64. BK=64, double-buffered 128KiB LDS.
// MODE 0: bf16 out = acc + bias                     (QKV)
// MODE 1: window-reverse; f32 out = resid + ls*(acc+bias)  (proj)
// MODE 2: f32 out = resid + ls*(acc+bias), resid may alias (fc2)
// MODE 3: GLU dual-half: B0 = h cols, B1 = gate cols; out bf16 = h*silu(gate)
// =====================================================================================
#define GBAR __builtin_amdgcn_s_barrier()
#define LGKM0                                  \
  do {                                         \
    asm volatile("s_waitcnt lgkmcnt(0)");      \
    __builtin_amdgcn_sched_barrier(0);         \
  } while (0)
#define VMCNT6 asm volatile("s_waitcnt vmcnt(6)" ::: "memory")

#define RD_A(qm, buf)                                                                       \
  do {                                                                                      \
    const char* ra_ = lds + (buf)*65536 + wr * 16384;                                       \
    _Pragma("unroll") for (int f_ = 0; f_ < 4; ++f_)                                        \
        _Pragma("unroll") for (int kk_ = 0; kk_ < 2; ++kk_)                                 \
            afr[f_][kk_] = *(const vbf8*)(ra_ + ((qm)*64 + f_ * 16 + cl) * 128 +            \
                                          (((kk_ * 4 + g) ^ (lane & 7)) << 4));             \
  } while (0)

#define RD_B(qn, buf)                                                                       \
  do {                                                                                      \
    const char* rb_ = lds + (buf)*65536 + 32768 + (wn >> 1) * 16384;                        \
    _Pragma("unroll") for (int f2_ = 0; f2_ < 2; ++f2_)                                     \
        _Pragma("unroll") for (int kk_ = 0; kk_ < 2; ++kk_)                                 \
            bfr[qn][f2_][kk_] = *(const vbf8*)(rb_ + ((wn & 1) * 64 + (qn)*32 + f2_ * 16 +  \
                                                      cl) * 128 +                           \
                                               (((kk_ * 4 + g) ^ (lane & 7)) << 4));        \
  } while (0)

#define QUAD(qm, qn)                                                                        \
  do {                                                                                      \
    __builtin_amdgcn_s_setprio(1);                                                          \
    _Pragma("unroll") for (int f_ = 0; f_ < 4; ++f_)                                        \
        _Pragma("unroll") for (int f2_ = 0; f2_ < 2; ++f2_)                                 \
            _Pragma("unroll") for (int kk_ = 0; kk_ < 2; ++kk_)                             \
                acc[(qm)*4 + f_][(qn)*2 + f2_] = __builtin_amdgcn_mfma_f32_16x16x32_bf16(   \
                    afr[f_][kk_], bfr[qn][f2_][kk_], acc[(qm)*4 + f_][(qn)*2 + f2_], 0, 0,  \
                    0);                                                                     \
    __builtin_amdgcn_s_setprio(0);                                                          \
  } while (0)

template <int MODE, int NT>
__global__ __launch_bounds__(512, 2) void k_gemm256(const __hip_bfloat16* __restrict__ A,
                                                    const __hip_bfloat16* __restrict__ BT,
                                                    const float* __restrict__ bias,
                                                    void* __restrict__ outp,
                                                    const float* __restrict__ resid,
                                                    const float* __restrict__ lsv,
                                                    const int K, const int ldOut) {
  __shared__ alignas(16) char lds[131072];
  const int nwg = gridDim.x;
  int bid = blockIdx.x;
  bid = (bid & 7) * (nwg >> 3) + (bid >> 3);  // bijective XCD swizzle (nwg % 8 == 0)
  const int bm = bid / NT, bn = bid % NT;
  const int tid = threadIdx.x, lane = tid & 63, wv = tid >> 6;
  const int wr = wv >> 2, wn = wv & 3;
  const int cl = lane & 15, g = lane >> 4;
  const int Kb = K * 2;
  const int nkt = K >> 6;
  const int L = nkt - 1;

  const char* Ab = (const char*)A + (size_t)bm * 256 * Kb;
  const char* AH0 = Ab;
  const char* AH1 = Ab + (size_t)128 * Kb;
  const char* B0;
  const char* B1;
  if (MODE == 3) {
    B0 = (const char*)BT + (size_t)(bn * 128) * Kb;
    B1 = (const char*)BT + (size_t)(INNERP + bn * 128) * Kb;
  } else {
    B0 = (const char*)BT + (size_t)(bn * 256) * Kb;
    B1 = B0 + (size_t)128 * Kb;
  }

  char* lA[2][2] = {{lds, lds + 16384}, {lds + 65536, lds + 81920}};
  char* lB[2][2] = {{lds + 32768, lds + 49152}, {lds + 98304, lds + 114688}};

  const int swz = ((lane & 7) ^ (lane >> 3)) << 4;
  const int srow0 = wv * 8 + (lane >> 3);

  auto STAGE = [&](const char* gb, int kt, char* reg) {
#pragma unroll
    for (int j = 0; j < 2; ++j) {
      const char* src = gb + (size_t)(srow0 + j * 64) * Kb + swz + kt * 128;
      __builtin_amdgcn_global_load_lds((const as1void*)src, (as3void*)(reg + wv * 1024 + j * 8192),
                                       16, 0, 0);
    }
  };

  vbf8 afr[4][2], bfr[2][2][2];
  vf4 acc[8][4] = {};

  // prologue: tile0 (4 halves) + tile1 {B0, A0, B1}; wait tile0, 3 halves in flight
  STAGE(AH0, 0, lA[0][0]);
  STAGE(B0, 0, lB[0][0]);
  STAGE(B1, 0, lB[0][1]);
  STAGE(AH1, 0, lA[0][1]);
  STAGE(B0, 1, lB[1][0]);
  STAGE(AH0, 1, lA[1][0]);
  STAGE(B1, 1, lB[1][1]);
  asm volatile("s_waitcnt vmcnt(6)" ::: "memory");
  __syncthreads();

  const int NIT = nkt >> 1;
  for (int it = 0; it < NIT; ++it) {
    const int t = 2 * it;
    // ---- K-tile t (buf0), phases 1-4
    RD_A(0, 0);
    RD_B(0, 0);
    STAGE(AH1, t + 1, lA[1][1]);
    GBAR;
    LGKM0;
    QUAD(0, 0);
    GBAR;

    RD_B(1, 0);
    STAGE(AH0, imin(t + 2, L), lA[0][0]);
    GBAR;
    LGKM0;
    QUAD(0, 1);
    GBAR;

    RD_A(1, 0);
    STAGE(B0, imin(t + 2, L), lB[0][0]);
    GBAR;
    LGKM0;
    QUAD(1, 0);
    GBAR;

    STAGE(B1, imin(t + 2, L), lB[0][1]);
    GBAR;
    QUAD(1, 1);
    VMCNT6;
    GBAR;

    // ---- K-tile t+1 (buf1), phases 5-8
    RD_A(0, 1);
    RD_B(0, 1);
    STAGE(AH1, imin(t + 2, L), lA[0][1]);
    GBAR;
    LGKM0;
    QUAD(0, 0);
    GBAR;

    RD_B(1, 1);
    STAGE(B0, imin(t + 3, L), lB[1][0]);
    GBAR;
    LGKM0;
    QUAD(0, 1);
    GBAR;

    RD_A(1, 1);
    STAGE(AH0, imin(t + 3, L), lA[1][0]);
    GBAR;
    LGKM0;
    QUAD(1, 0);
    GBAR;

    STAGE(B1, imin(t + 3, L), lB[1][1]);
    GBAR;
    QUAD(1, 1);
    VMCNT6;
    GBAR;
  }

  // drain in-flight stages; keep epilogue loads below this point
  asm volatile("s_waitcnt vmcnt(0)" ::: "memory");
  __builtin_amdgcn_sched_barrier(0);

  const int rl4 = (lane >> 4) << 2;

  if (MODE == 0) {
    const int rbase = bm * 256 + wr * 128;
    const int cbase = bn * 256 + wn * 64;
    __hip_bfloat16* ob = (__hip_bfloat16*)outp;
    float bz[4];
#pragma unroll
    for (int n = 0; n < 4; ++n) bz[n] = bias[cbase + n * 16 + cl];
#pragma unroll
    for (int m = 0; m < 8; ++m)
#pragma unroll
      for (int j = 0; j < 4; ++j) {
        const int r = rbase + m * 16 + rl4 + j;
#pragma unroll
        for (int n = 0; n < 4; ++n)
          ob[(size_t)r * ldOut + cbase + n * 16 + cl] = __float2bfloat16(acc[m][n][j] + bz[n]);
      }
  } else if (MODE == 1 || MODE == 2) {
    const int rbase = bm * 256 + wr * 128;
    const int cbase = bn * 256 + wn * 64;
    float* of = (float*)outp;
    float bz[4], lz[4];
#pragma unroll
    for (int n = 0; n < 4; ++n) {
      bz[n] = bias[cbase + n * 16 + cl];
      lz[n] = lsv[cbase + n * 16 + cl];
    }
#pragma unroll
    for (int m = 0; m < 8; ++m)
#pragma unroll
      for (int j = 0; j < 4; ++j) {
        const int r = rbase + m * 16 + rl4 + j;
        size_t orow;
        if (MODE == 1) {
          int mwin = r >> 6, t2 = r & 63;
          int b = mwin / 144, mm = mwin % 144;
          int wh = mm / 12, ww = mm % 12;
          int h = wh * 8 + (t2 >> 3), w = ww * 8 + (t2 & 7);
          orow = (size_t)((b * 96 + h) * 96 + w);
        } else {
          orow = (size_t)r;
        }
#pragma unroll
        for (int n = 0; n < 4; ++n) {
          const int c = cbase + n * 16 + cl;
          of[orow * DIM + c] = resid[orow * DIM + c] + lz[n] * (acc[m][n][j] + bz[n]);
        }
      }
  } else {  // MODE 3: GLU
    float* xg = (float*)lds;
    const int pair = wr * 2 + (wn & 1);
    __syncthreads();
    if (wn >= 2) {
#pragma unroll
      for (int m = 0; m < 8; ++m)
#pragma unroll
        for (int n = 0; n < 4; ++n)
#pragma unroll
          for (int j = 0; j < 4; ++j)
            xg[pair * 8192 + (m * 16 + n * 4 + j) * 64 + lane] = acc[m][n][j];
    }
    __syncthreads();
    if (wn < 2) {
      const int rbase = bm * 256 + wr * 128;
      const int cbase = bn * 128 + wn * 64;
      __hip_bfloat16* ob = (__hip_bfloat16*)outp;
      float bh[4], bg[4];
#pragma unroll
      for (int n = 0; n < 4; ++n) {
        bh[n] = bias[cbase + n * 16 + cl];
        bg[n] = bias[INNERP + cbase + n * 16 + cl];
      }
#pragma unroll
      for (int m = 0; m < 8; ++m)
#pragma unroll
        for (int n = 0; n < 4; ++n)
#pragma unroll
          for (int j = 0; j < 4; ++j) {
            const float gv = xg[pair * 8192 + (m * 16 + n * 4 + j) * 64 + lane] + bg[n];
            const float hv = acc[m][n][j] + bh[n];
            const float sg = 1.0f / (1.0f + __expf(-gv));
            const int r = rbase + m * 16 + rl4 + j;
            ob[(size_t)r * ldOut + cbase + n * 16 + cl] = __float2bfloat16(hv * gv * sg);
          }
    }
  }
}

// ---------------- attention: MFMA, one wave per (window, head) ----------------
__global__ __launch_bounds__(256, 2) void k_attn_mfma(const __hip_bfloat16* __restrict__ qkv,
                                                      __hip_bfloat16* __restrict__ o) {
  __shared__ __hip_bfloat16 sm[4][6912];
  const int wave = threadIdx.x >> 6, lane = threadIdx.x & 63;
  const int task = blockIdx.x * 4 + wave;
  const int w = task >> 4, hd = task & 15;
  const int g = lane >> 4, c = lane & 15;
  __hip_bfloat16* smp = sm[wave];
  __hip_bfloat16* smv = smp + 4608;

  const __hip_bfloat16* base = qkv + (size_t)w * 64 * 1536 + hd * 32;

  vbf8 qf[4], kf[4];
#pragma unroll
  for (int i = 0; i < 4; ++i) {
    const __hip_bfloat16* qrow = base + (size_t)(i * 16 + c) * 1536 + g * 8;
    qf[i] = *(const vbf8*)qrow;
    kf[i] = *(const vbf8*)(qrow + 512);
  }

  {
    const __hip_bfloat16* vrow = base + (size_t)lane * 1536 + 1024;
    union {
      vbf8 v;
      ushort e[8];
    } uv[4];
#pragma unroll
    for (int i = 0; i < 4; ++i) uv[i].v = *(const vbf8*)(vrow + i * 8);
#pragma unroll
    for (int d = 0; d < 32; ++d)
      ((ushort*)smv)[d * 72 + lane] = uv[d >> 3].e[d & 7];
  }

  vf4 st[4][4];
#pragma unroll
  for (int iq = 0; iq < 4; ++iq)
#pragma unroll
    for (int it = 0; it < 4; ++it) {
      vf4 z = {};
      st[iq][it] = __builtin_amdgcn_mfma_f32_16x16x32_bf16(qf[iq], kf[it], z, 0, 0, 0);
    }

  float inv[4][4];
#pragma unroll
  for (int iq = 0; iq < 4; ++iq) {
#pragma unroll
    for (int j = 0; j < 4; ++j) {
      float m = fmaxf(fmaxf(st[iq][0][j], st[iq][1][j]), fmaxf(st[iq][2][j], st[iq][3][j]));
      m = fmaxf(m, __shfl_xor(m, 1));
      m = fmaxf(m, __shfl_xor(m, 2));
      m = fmaxf(m, __shfl_xor(m, 4));
      m = fmaxf(m, __shfl_xor(m, 8));
      float s = 0.f;
#pragma unroll
      for (int it = 0; it < 4; ++it) {
        const float e = __expf((st[iq][it][j] - m) * 0.17677669529663687f);
        st[iq][it][j] = e;
        s += e;
      }
      s += __shfl_xor(s, 1);
      s += __shfl_xor(s, 2);
      s += __shfl_xor(s, 4);
      s += __shfl_xor(s, 8);
      inv[iq][j] = 1.0f / s;
    }
  }

#pragma unroll
  for (int iq = 0; iq < 4; ++iq)
#pragma unroll
    for (int j = 0; j < 4; ++j) {
      const int q = iq * 16 + g * 4 + j;
#pragma unroll
      for (int it = 0; it < 4; ++it)
        smp[q * 72 + it * 16 + c] = __float2bfloat16(st[iq][it][j]);
    }

  vf4 ot[4][2] = {};
#pragma unroll
  for (int ks = 0; ks < 2; ++ks) {
    vbf8 pf[4], vfr[2];
#pragma unroll
    for (int iq = 0; iq < 4; ++iq)
      pf[iq] = *(const vbf8*)(smp + (iq * 16 + c) * 72 + ks * 32 + g * 8);
#pragma unroll
    for (int dt = 0; dt < 2; ++dt)
      vfr[dt] = *(const vbf8*)(smv + (dt * 16 + c) * 72 + ks * 32 + g * 8);
#pragma unroll
    for (int iq = 0; iq < 4; ++iq)
#pragma unroll
      for (int dt = 0; dt < 2; ++dt)
        ot[iq][dt] = __builtin_amdgcn_mfma_f32_16x16x32_bf16(pf[iq], vfr[dt], ot[iq][dt], 0, 0, 0);
  }

#pragma unroll
  for (int iq = 0; iq < 4; ++iq)
#pragma unroll
    for (int dt = 0; dt < 2; ++dt)
#pragma unroll
      for (int j = 0; j < 4; ++j) {
        const int q = iq * 16 + g * 4 + j;
        smp[q * 72 + dt * 16 + c] = __float2bfloat16(ot[iq][dt][j] * inv[iq][j]);
      }
  __hip_bfloat16* ob = o + (size_t)w * 64 * 512 + hd * 32;
#pragma unroll
  for (int i = 0; i < 4; ++i) {
    const int idx = i * 64 + lane;
    const int row = idx >> 2, chunk = idx & 3;
    const vbf8 val = *(const vbf8*)(smp + row * 72 + chunk * 8);
    *(vbf8*)(ob + (size_t)row * 512 + chunk * 8) = val;
  }
}

// ---------------- launch ----------------
extern "C" void kernel_launch(void* const* d_in, const int* in_sizes, int n_in, void* d_out,
                              int out_size, void* d_ws, size_t ws_size, hipStream_t stream) {
  const float* x = (const float*)d_in[0];
  const float* n1g = (const float*)d_in[1];
  const float* n1b = (const float*)d_in[2];
  const float* qkv_w = (const float*)d_in[3];
  const float* qkv_b = (const float*)d_in[4];
  const float* proj_w = (const float*)d_in[5];
  const float* proj_b = (const float*)d_in[6];
  const float* ls1 = (const float*)d_in[7];
  const float* n2g = (const float*)d_in[8];
  const float* n2b = (const float*)d_in[9];
  const float* glu_w = (const float*)d_in[10];
  const float* glu_b = (const float*)d_in[11];
  const float* fc2_w = (const float*)d_in[12];
  const float* fc2_b = (const float*)d_in[13];
  const float* ls2 = (const float*)d_in[14];

  if (ws_size < 308424704u) return;

  char* ws = (char*)d_ws;
  __hip_bfloat16* wTq = (__hip_bfloat16*)(ws + 0);           // [1536][512]
  __hip_bfloat16* wTp = (__hip_bfloat16*)(ws + 1572864);     // [512][512]
  __hip_bfloat16* wTg = (__hip_bfloat16*)(ws + 2097152);     // [2816][512], padded
  __hip_bfloat16* wTf = (__hip_bfloat16*)(ws + 4980736);     // [512][1408], padded
  float* gbias = (float*)(ws + 6422528);                     // [2816]
  __hip_bfloat16* ybuf = (__hip_bfloat16*)(ws + 6434816);    // [73728][512]
  __hip_bfloat16* qkvbuf = (__hip_bfloat16*)(ws + 81932288); // [73728][1536] / h [73728][1408]
  float* x1 = (float*)d_out;

  hipMemsetAsync(wTg, 0, 2883584, stream);
  hipMemsetAsync(wTf, 0, 1441792, stream);
  hipMemsetAsync(gbias, 0, 11264, stream);

  dim3 tb(32, 8);
  k_transpose<<<dim3(48, 16), tb, 0, stream>>>(qkv_w, wTq, 512, 1536, 512, 1 << 30);
  k_transpose<<<dim3(16, 16), tb, 0, stream>>>(proj_w, wTp, 512, 512, 512, 1 << 30);
  k_transpose<<<dim3(84, 16), tb, 0, stream>>>(glu_w, wTg, 512, 2688, 512, INNER);
  k_transpose<<<dim3(16, 42), tb, 0, stream>>>(fc2_w, wTf, 1344, 512, 1408, 1 << 30);
  k_padbias<<<11, 256, 0, stream>>>(glu_b, gbias);

  k_ln<true><<<18432, 256, 0, stream>>>(x, n1g, n1b, ybuf);
  k_gemm256<0, 6><<<1728, 512, 0, stream>>>(ybuf, wTq, qkv_b, qkvbuf, nullptr, nullptr, 512, 1536);
  k_attn_mfma<<<4608, 256, 0, stream>>>(qkvbuf, ybuf);
  k_gemm256<1, 2><<<576, 512, 0, stream>>>(ybuf, wTp, proj_b, (void*)x1, x, ls1, 512, 512);
  k_ln<false><<<18432, 256, 0, stream>>>(x1, n2g, n2b, ybuf);
  k_gemm256<3, 11><<<3168, 512, 0, stream>>>(ybuf, wTg, gbias, qkvbuf, nullptr, nullptr, 512, INNERP);
  k_gemm256<2, 2><<<576, 512, 0, stream>>>(qkvbuf, wTf, fc2_b, d_out, x1, ls2, INNERP, 512);
}

// Round 4
// 780.255 us; speedup vs baseline: 1.1816x; 1.1816x over previous
//
#include <hip/hip_runtime.h>
#include <hip/hip_bf16.h>
#include <stdint.h>

#define DIM 512
#define HEADS 16
#define NTOK 73728
#define INNER 1344

typedef __attribute__((ext_vector_type(8))) short vbf8;
typedef __attribute__((ext_vector_type(4))) float vf4;

typedef __attribute__((address_space(1))) void as1void;
typedef __attribute__((address_space(3))) void as3void;

// ---------------- weight transpose + bf16 cast: WT[n][k] = W[k][n] ----------------
__global__ void k_transpose(const float* __restrict__ Wsrc, __hip_bfloat16* __restrict__ WT,
                            int K, int N) {
  __shared__ float tile[32][33];
  const int tx = threadIdx.x, ty = threadIdx.y;
  const int n0 = blockIdx.x * 32, k0 = blockIdx.y * 32;
#pragma unroll
  for (int i = 0; i < 32; i += 8) {
    int k = k0 + ty + i, n = n0 + tx;
    if (k < K && n < N) tile[ty + i][tx] = Wsrc[(size_t)k * N + n];
  }
  __syncthreads();
#pragma unroll
  for (int i = 0; i < 32; i += 8) {
    int n = n0 + ty + i, k = k0 + tx;
    if (n < N && k < K) WT[(size_t)n * K + k] = __float2bfloat16(tile[tx][ty + i]);
  }
}

// ---------------- LayerNorm (+ optional window partition), fp32 -> bf16 ----------------
template <bool PART>
__global__ __launch_bounds__(256) void k_ln(const float* __restrict__ x,
                                            const float* __restrict__ gw,
                                            const float* __restrict__ bw,
                                            __hip_bfloat16* __restrict__ y) {
  const int wave = threadIdx.x >> 6, lane = threadIdx.x & 63;
  const int tok = blockIdx.x * 4 + wave;
  const float* xr = x + (size_t)tok * DIM + lane * 8;
  const float4 v0 = *(const float4*)xr;
  const float4 v1 = *(const float4*)(xr + 4);
  float s = v0.x + v0.y + v0.z + v0.w + v1.x + v1.y + v1.z + v1.w;
  float ss = v0.x * v0.x + v0.y * v0.y + v0.z * v0.z + v0.w * v0.w +
             v1.x * v1.x + v1.y * v1.y + v1.z * v1.z + v1.w * v1.w;
#pragma unroll
  for (int off = 32; off > 0; off >>= 1) {
    s += __shfl_xor(s, off);
    ss += __shfl_xor(ss, off);
  }
  const float mu = s * (1.0f / DIM);
  const float rs = rsqrtf(ss * (1.0f / DIM) - mu * mu + 1e-6f);
  size_t orow;
  if (PART) {
    int b = tok / 9216, rem = tok % 9216;
    int h = rem / 96, w = rem % 96;
    orow = (size_t)(((b * 12 + (h >> 3)) * 12 + (w >> 3)) * 64 + (h & 7) * 8 + (w & 7));
  } else {
    orow = (size_t)tok;
  }
  const float4 g0 = *(const float4*)(gw + lane * 8);
  const float4 g1 = *(const float4*)(gw + lane * 8 + 4);
  const float4 b0 = *(const float4*)(bw + lane * 8);
  const float4 b1 = *(const float4*)(bw + lane * 8 + 4);
  const float vals[8] = {v0.x, v0.y, v0.z, v0.w, v1.x, v1.y, v1.z, v1.w};
  const float gg[8] = {g0.x, g0.y, g0.z, g0.w, g1.x, g1.y, g1.z, g1.w};
  const float bb[8] = {b0.x, b0.y, b0.z, b0.w, b1.x, b1.y, b1.z, b1.w};
  union {
    vbf8 v;
    __hip_bfloat16 e[8];
  } po;
#pragma unroll
  for (int j = 0; j < 8; ++j) po.e[j] = __float2bfloat16((vals[j] - mu) * rs * gg[j] + bb[j]);
  *(vbf8*)(y + orow * DIM + lane * 8) = po.v;
}

// ---------------- LDS staging via global_load_lds, source pre-swizzled (T2) ----------------
template <int ROWS>
__device__ __forceinline__ void stage_lds(const __hip_bfloat16* __restrict__ g, int ldK,
                                          char* lds, int wave, int lane) {
  constexpr int RPW = ROWS / 4;  // rows per wave
  const int r0 = wave * RPW;
  const int ro = lane >> 3;  // row within 8-row group
  const int pb = lane & 7;   // physical 16B block
  const char* src = (const char*)g + (size_t)(r0 + ro) * (size_t)(ldK * 2) + ((pb ^ ro) << 4);
  char* dst = lds + r0 * 128;
#pragma unroll
  for (int c = 0; c < RPW; c += 8) {
    __builtin_amdgcn_global_load_lds((const as1void*)(src + (size_t)c * (size_t)(ldK * 2)),
                                     (as3void*)(dst + c * 128), 16, 0, 0);
  }
}

__device__ __forceinline__ const vbf8* lds_frag(const char* base, int row, int cbbyte, int xmask) {
  return (const vbf8*)(base + row * 128 + (cbbyte ^ xmask));
}

// ---------------- 128x128 GEMM, C = A[M,K] * BT[N,K]^T, epilogue by MODE ----------------
// MODE 0: out bf16 = acc + bias           (QKV)
// MODE 1: window-reverse; outf = resid + ls*(acc+bias)  (proj)
// MODE 2: outf = resid + ls*(acc+bias)    (fc2; resid may alias outf)
template <int MODE, int NT>
__global__ __launch_bounds__(256, 2) void k_gemm128(const __hip_bfloat16* __restrict__ A,
                                                    const __hip_bfloat16* __restrict__ BT,
                                                    const float* __restrict__ bias,
                                                    void* __restrict__ outp,
                                                    const float* __restrict__ resid,
                                                    const float* __restrict__ lsv, int K, int N) {
  __shared__ alignas(16) char As[128 * 128];
  __shared__ alignas(16) char Bs[128 * 128];
  const int nwg = gridDim.x;
  int bid = blockIdx.x;
  bid = (bid & 7) * (nwg >> 3) + (bid >> 3);  // bijective XCD swizzle (nwg % 8 == 0)
  const int bm = bid / NT, bn = bid % NT;
  const int tid = threadIdx.x;
  const int wave = tid >> 6, lane = tid & 63;
  const int wr = wave >> 1, wc = wave & 1;
  vf4 acc[4][4] = {};

  const __hip_bfloat16* Ab = A + (size_t)bm * 128 * K;
  const __hip_bfloat16* Bb = BT + (size_t)bn * 128 * K;
  const int arow = wr * 64 + (lane & 15);
  const int brow = wc * 64 + (lane & 15);
  const int xmask = (lane & 7) << 4;
  const int cb0 = (lane >> 4) << 4;

  for (int ko = 0; ko < K; ko += 64) {
    __syncthreads();
    stage_lds<128>(Ab + ko, K, As, wave, lane);
    stage_lds<128>(Bb + ko, K, Bs, wave, lane);
    __syncthreads();
#pragma unroll
    for (int ks = 0; ks < 2; ++ks) {
      vbf8 af[4], bfr[4];
#pragma unroll
      for (int i = 0; i < 4; ++i) {
        af[i] = *lds_frag(As, arow + i * 16, cb0 + ks * 64, xmask);
        bfr[i] = *lds_frag(Bs, brow + i * 16, cb0 + ks * 64, xmask);
      }
#pragma unroll
      for (int mi = 0; mi < 4; ++mi)
#pragma unroll
        for (int ni = 0; ni < 4; ++ni)
          acc[mi][ni] = __builtin_amdgcn_mfma_f32_16x16x32_bf16(af[mi], bfr[ni], acc[mi][ni], 0, 0, 0);
    }
  }

  const int rl = (lane >> 4) << 2;
  const int cl = lane & 15;
  const int rbase = bm * 128 + wr * 64;
  const int cbase = bn * 128 + wc * 64;
#pragma unroll
  for (int mi = 0; mi < 4; ++mi) {
#pragma unroll
    for (int j = 0; j < 4; ++j) {
      const int r = rbase + mi * 16 + rl + j;
      size_t orow;
      if (MODE == 1) {
        int m = r >> 6, t = r & 63;
        int b = m / 144, mm = m % 144;
        int wh = mm / 12, ww = mm % 12;
        int h = wh * 8 + (t >> 3), w = ww * 8 + (t & 7);
        orow = (size_t)((b * 96 + h) * 96 + w);
      } else {
        orow = (size_t)r;
      }
#pragma unroll
      for (int ni = 0; ni < 4; ++ni) {
        const int c = cbase + ni * 16 + cl;
        const float v = acc[mi][ni][j] + bias[c];
        if (MODE == 0) {
          ((__hip_bfloat16*)outp)[(size_t)r * N + c] = __float2bfloat16(v);
        } else {
          float* of = (float*)outp;
          of[orow * DIM + c] = resid[orow * DIM + c] + lsv[c] * v;
        }
      }
    }
  }
}

// ---------------- GLU GEMM: dual-half (h, gate) with fused silu ----------------
__global__ __launch_bounds__(256, 2) void k_gemm_glu(const __hip_bfloat16* __restrict__ A,
                                                     const __hip_bfloat16* __restrict__ BT,
                                                     const float* __restrict__ bias,
                                                     __hip_bfloat16* __restrict__ hout) {
  __shared__ alignas(16) char As[128 * 128];
  __shared__ alignas(16) char B0s[64 * 128];
  __shared__ alignas(16) char B1s[64 * 128];
  const int K = DIM;
  const int nwg = gridDim.x;
  int bid = blockIdx.x;
  bid = (bid & 7) * (nwg >> 3) + (bid >> 3);  // bijective XCD swizzle
  const int bm = bid / 21, bn = bid % 21;
  const int tid = threadIdx.x;
  const int wave = tid >> 6, lane = tid & 63;
  const int wr = wave >> 1, wc = wave & 1;
  vf4 a0[4][2] = {}, a1[4][2] = {};

  const __hip_bfloat16* Ab = A + (size_t)bm * 128 * K;
  const __hip_bfloat16* Bb0 = BT + (size_t)(bn * 64) * K;
  const __hip_bfloat16* Bb1 = BT + (size_t)(INNER + bn * 64) * K;
  const int arow = wr * 64 + (lane & 15);
  const int brow = wc * 32 + (lane & 15);
  const int xmask = (lane & 7) << 4;
  const int cb0 = (lane >> 4) << 4;

  for (int ko = 0; ko < K; ko += 64) {
    __syncthreads();
    stage_lds<128>(Ab + ko, K, As, wave, lane);
    stage_lds<64>(Bb0 + ko, K, B0s, wave, lane);
    stage_lds<64>(Bb1 + ko, K, B1s, wave, lane);
    __syncthreads();
#pragma unroll
    for (int ks = 0; ks < 2; ++ks) {
      vbf8 af[4], b0f[2], b1f[2];
#pragma unroll
      for (int i = 0; i < 4; ++i) af[i] = *lds_frag(As, arow + i * 16, cb0 + ks * 64, xmask);
#pragma unroll
      for (int i = 0; i < 2; ++i) {
        b0f[i] = *lds_frag(B0s, brow + i * 16, cb0 + ks * 64, xmask);
        b1f[i] = *lds_frag(B1s, brow + i * 16, cb0 + ks * 64, xmask);
      }
#pragma unroll
      for (int mi = 0; mi < 4; ++mi)
#pragma unroll
        for (int ni = 0; ni < 2; ++ni) {
          a0[mi][ni] = __builtin_amdgcn_mfma_f32_16x16x32_bf16(af[mi], b0f[ni], a0[mi][ni], 0, 0, 0);
          a1[mi][ni] = __builtin_amdgcn_mfma_f32_16x16x32_bf16(af[mi], b1f[ni], a1[mi][ni], 0, 0, 0);
        }
    }
  }

  const int rl = (lane >> 4) << 2;
  const int cl = lane & 15;
  const int rbase = bm * 128 + wr * 64;
  const int cbase = bn * 64 + wc * 32;
#pragma unroll
  for (int mi = 0; mi < 4; ++mi)
#pragma unroll
    for (int j = 0; j < 4; ++j) {
      const int r = rbase + mi * 16 + rl + j;
#pragma unroll
      for (int ni = 0; ni < 2; ++ni) {
        const int c = cbase + ni * 16 + cl;
        const float a = a0[mi][ni][j] + bias[c];
        const float g = a1[mi][ni][j] + bias[INNER + c];
        const float sg = 1.0f / (1.0f + __expf(-g));
        hout[(size_t)r * INNER + c] = __float2bfloat16(a * g * sg);
      }
    }
}

// ---------------- attention: MFMA, one wave per (window, head) ----------------
__global__ __launch_bounds__(256, 2) void k_attn_mfma(const __hip_bfloat16* __restrict__ qkv,
                                                      __hip_bfloat16* __restrict__ o) {
  __shared__ __hip_bfloat16 sm[4][6912];
  const int wave = threadIdx.x >> 6, lane = threadIdx.x & 63;
  const int task = blockIdx.x * 4 + wave;
  const int w = task >> 4, hd = task & 15;
  const int g = lane >> 4, c = lane & 15;
  __hip_bfloat16* smp = sm[wave];
  __hip_bfloat16* smv = smp + 4608;

  const __hip_bfloat16* base = qkv + (size_t)w * 64 * 1536 + hd * 32;

  vbf8 qf[4], kf[4];
#pragma unroll
  for (int i = 0; i < 4; ++i) {
    const __hip_bfloat16* qrow = base + (size_t)(i * 16 + c) * 1536 + g * 8;
    qf[i] = *(const vbf8*)qrow;
    kf[i] = *(const vbf8*)(qrow + 512);
  }

  {
    const __hip_bfloat16* vrow = base + (size_t)lane * 1536 + 1024;
    union {
      vbf8 v;
      ushort e[8];
    } uv[4];
#pragma unroll
    for (int i = 0; i < 4; ++i) uv[i].v = *(const vbf8*)(vrow + i * 8);
#pragma unroll
    for (int d = 0; d < 32; ++d)
      ((ushort*)smv)[d * 72 + lane] = uv[d >> 3].e[d & 7];
  }

  vf4 st[4][4];
#pragma unroll
  for (int iq = 0; iq < 4; ++iq)
#pragma unroll
    for (int it = 0; it < 4; ++it) {
      vf4 z = {};
      st[iq][it] = __builtin_amdgcn_mfma_f32_16x16x32_bf16(qf[iq], kf[it], z, 0, 0, 0);
    }

  float inv[4][4];
#pragma unroll
  for (int iq = 0; iq < 4; ++iq) {
#pragma unroll
    for (int j = 0; j < 4; ++j) {
      float m = fmaxf(fmaxf(st[iq][0][j], st[iq][1][j]), fmaxf(st[iq][2][j], st[iq][3][j]));
      m = fmaxf(m, __shfl_xor(m, 1));
      m = fmaxf(m, __shfl_xor(m, 2));
      m = fmaxf(m, __shfl_xor(m, 4));
      m = fmaxf(m, __shfl_xor(m, 8));
      float s = 0.f;
#pragma unroll
      for (int it = 0; it < 4; ++it) {
        const float e = __expf((st[iq][it][j] - m) * 0.17677669529663687f);
        st[iq][it][j] = e;
        s += e;
      }
      s += __shfl_xor(s, 1);
      s += __shfl_xor(s, 2);
      s += __shfl_xor(s, 4);
      s += __shfl_xor(s, 8);
      inv[iq][j] = 1.0f / s;
    }
  }

#pragma unroll
  for (int iq = 0; iq < 4; ++iq)
#pragma unroll
    for (int j = 0; j < 4; ++j) {
      const int q = iq * 16 + g * 4 + j;
#pragma unroll
      for (int it = 0; it < 4; ++it)
        smp[q * 72 + it * 16 + c] = __float2bfloat16(st[iq][it][j]);
    }

  vf4 ot[4][2] = {};
#pragma unroll
  for (int ks = 0; ks < 2; ++ks) {
    vbf8 pf[4], vfr[2];
#pragma unroll
    for (int iq = 0; iq < 4; ++iq)
      pf[iq] = *(const vbf8*)(smp + (iq * 16 + c) * 72 + ks * 32 + g * 8);
#pragma unroll
    for (int dt = 0; dt < 2; ++dt)
      vfr[dt] = *(const vbf8*)(smv + (dt * 16 + c) * 72 + ks * 32 + g * 8);
#pragma unroll
    for (int iq = 0; iq < 4; ++iq)
#pragma unroll
      for (int dt = 0; dt < 2; ++dt)
        ot[iq][dt] = __builtin_amdgcn_mfma_f32_16x16x32_bf16(pf[iq], vfr[dt], ot[iq][dt], 0, 0, 0);
  }

#pragma unroll
  for (int iq = 0; iq < 4; ++iq)
#pragma unroll
    for (int dt = 0; dt < 2; ++dt)
#pragma unroll
      for (int j = 0; j < 4; ++j) {
        const int q = iq * 16 + g * 4 + j;
        smp[q * 72 + dt * 16 + c] = __float2bfloat16(ot[iq][dt][j] * inv[iq][j]);
      }
  __hip_bfloat16* ob = o + (size_t)w * 64 * 512 + hd * 32;
#pragma unroll
  for (int i = 0; i < 4; ++i) {
    const int idx = i * 64 + lane;
    const int row = idx >> 2, chunk = idx & 3;
    const vbf8 val = *(const vbf8*)(smp + row * 72 + chunk * 8);
    *(vbf8*)(ob + (size_t)row * 512 + chunk * 8) = val;
  }
}

// ---------------- launch ----------------
extern "C" void kernel_launch(void* const* d_in, const int* in_sizes, int n_in, void* d_out,
                              int out_size, void* d_ws, size_t ws_size, hipStream_t stream) {
  const float* x = (const float*)d_in[0];
  const float* n1g = (const float*)d_in[1];
  const float* n1b = (const float*)d_in[2];
  const float* qkv_w = (const float*)d_in[3];
  const float* qkv_b = (const float*)d_in[4];
  const float* proj_w = (const float*)d_in[5];
  const float* proj_b = (const float*)d_in[6];
  const float* ls1 = (const float*)d_in[7];
  const float* n2g = (const float*)d_in[8];
  const float* n2b = (const float*)d_in[9];
  const float* glu_w = (const float*)d_in[10];
  const float* glu_b = (const float*)d_in[11];
  const float* fc2_w = (const float*)d_in[12];
  const float* fc2_b = (const float*)d_in[13];
  const float* ls2 = (const float*)d_in[14];

  if (ws_size < 308281344u) return;  // need ~308 MB scratch

  char* ws = (char*)d_ws;
  __hip_bfloat16* wTq = (__hip_bfloat16*)(ws + 0);           // 1536x512
  __hip_bfloat16* wTp = (__hip_bfloat16*)(ws + 1572864);     // 512x512
  __hip_bfloat16* wTg = (__hip_bfloat16*)(ws + 2097152);     // 2688x512
  __hip_bfloat16* wTf = (__hip_bfloat16*)(ws + 4849664);     // 512x1344
  __hip_bfloat16* ybuf = (__hip_bfloat16*)(ws + 6291456);    // 73728x512
  __hip_bfloat16* qkvbuf = (__hip_bfloat16*)(ws + 81788928); // 73728x1536
  float* x1 = (float*)d_out;

  dim3 tb(32, 8);
  k_transpose<<<dim3(48, 16), tb, 0, stream>>>(qkv_w, wTq, 512, 1536);
  k_transpose<<<dim3(16, 16), tb, 0, stream>>>(proj_w, wTp, 512, 512);
  k_transpose<<<dim3(84, 16), tb, 0, stream>>>(glu_w, wTg, 512, 2688);
  k_transpose<<<dim3(16, 42), tb, 0, stream>>>(fc2_w, wTf, 1344, 512);

  k_ln<true><<<18432, 256, 0, stream>>>(x, n1g, n1b, ybuf);
  k_gemm128<0, 12><<<576 * 12, 256, 0, stream>>>(ybuf, wTq, qkv_b, qkvbuf, nullptr, nullptr, 512, 1536);
  k_attn_mfma<<<4608, 256, 0, stream>>>(qkvbuf, ybuf);
  k_gemm128<1, 4><<<576 * 4, 256, 0, stream>>>(ybuf, wTp, proj_b, (void*)x1, x, ls1, 512, 512);
  k_ln<false><<<18432, 256, 0, stream>>>(x1, n2g, n2b, ybuf);
  k_gemm_glu<<<576 * 21, 256, 0, stream>>>(ybuf, wTg, glu_b, qkvbuf);
  k_gemm128<2, 4><<<576 * 4, 256, 0, stream>>>(qkvbuf, wTf, fc2_b, d_out, x1, ls2, 1344, 512);
}

// Round 5
// 577.868 us; speedup vs baseline: 1.5954x; 1.3502x over previous
//
#include <hip/hip_runtime.h>
#include <hip/hip_bf16.h>
#include <stdint.h>

#define DIM 512
#define HEADS 16
#define NTOK 73728
#define INNER 1344
#define INNERP 1408

typedef __attribute__((ext_vector_type(8))) short vbf8;
typedef __attribute__((ext_vector_type(4))) float vf4;
typedef __attribute__((ext_vector_type(4))) int v4i;
typedef __attribute__((ext_vector_type(8))) int v8i;

typedef __attribute__((address_space(1))) void as1void;
typedef __attribute__((address_space(3))) void as3void;

__device__ __forceinline__ unsigned pk4fp8(float a, float b, float c, float d) {
  int v = __builtin_amdgcn_cvt_pk_fp8_f32(a, b, 0, false);
  v = __builtin_amdgcn_cvt_pk_fp8_f32(c, d, v, true);
  return (unsigned)v;
}

// ---------------- weight transpose + fp8 cast: WT[n'][k] = W[k][n] ----------------
__global__ void k_transpose(const float* __restrict__ Wsrc, uint8_t* __restrict__ WT,
                            int K, int N, int ldOut, int nsplit) {
  __shared__ float tile[32][33];
  const int tx = threadIdx.x, ty = threadIdx.y;
  const int n0 = blockIdx.x * 32, k0 = blockIdx.y * 32;
#pragma unroll
  for (int i = 0; i < 32; i += 8) {
    int k = k0 + ty + i, n = n0 + tx;
    if (k < K && n < N) tile[ty + i][tx] = Wsrc[(size_t)k * N + n];
  }
  __syncthreads();
#pragma unroll
  for (int i = 0; i < 32; i += 8) {
    int n = n0 + ty + i, k = k0 + tx;
    if (n < N && k < K) {
      int np = n + (n >= nsplit ? 64 : 0);
      float v = tile[tx][ty + i];
      WT[(size_t)np * ldOut + k] =
          (uint8_t)(__builtin_amdgcn_cvt_pk_fp8_f32(v, v, 0, false) & 0xff);
    }
  }
}

// ---------------- pad GLU bias into [2816] ----------------
__global__ void k_padbias(const float* __restrict__ b, float* __restrict__ o) {
  int c = blockIdx.x * 256 + threadIdx.x;
  if (c < INNER) o[c] = b[c];
  else if (c >= INNERP && c < INNERP + INNER) o[c] = b[c - 64];
  else if (c < 2816) o[c] = 0.0f;
}

// ---------------- LayerNorm (+ optional window partition), fp32 -> fp8 ----------------
template <bool PART>
__global__ __launch_bounds__(256) void k_ln(const float* __restrict__ x,
                                            const float* __restrict__ gw,
                                            const float* __restrict__ bw,
                                            uint8_t* __restrict__ y) {
  const int wave = threadIdx.x >> 6, lane = threadIdx.x & 63;
  const int tok = blockIdx.x * 4 + wave;
  const float* xr = x + (size_t)tok * DIM + lane * 8;
  const float4 v0 = *(const float4*)xr;
  const float4 v1 = *(const float4*)(xr + 4);
  float s = v0.x + v0.y + v0.z + v0.w + v1.x + v1.y + v1.z + v1.w;
  float ss = v0.x * v0.x + v0.y * v0.y + v0.z * v0.z + v0.w * v0.w +
             v1.x * v1.x + v1.y * v1.y + v1.z * v1.z + v1.w * v1.w;
#pragma unroll
  for (int off = 32; off > 0; off >>= 1) {
    s += __shfl_xor(s, off);
    ss += __shfl_xor(ss, off);
  }
  const float mu = s * (1.0f / DIM);
  const float rs = rsqrtf(ss * (1.0f / DIM) - mu * mu + 1e-6f);
  size_t orow;
  if (PART) {
    int b = tok / 9216, rem = tok % 9216;
    int h = rem / 96, w = rem % 96;
    orow = (size_t)(((b * 12 + (h >> 3)) * 12 + (w >> 3)) * 64 + (h & 7) * 8 + (w & 7));
  } else {
    orow = (size_t)tok;
  }
  const float4 g0 = *(const float4*)(gw + lane * 8);
  const float4 g1 = *(const float4*)(gw + lane * 8 + 4);
  const float4 b0 = *(const float4*)(bw + lane * 8);
  const float4 b1 = *(const float4*)(bw + lane * 8 + 4);
  const float vals[8] = {v0.x, v0.y, v0.z, v0.w, v1.x, v1.y, v1.z, v1.w};
  const float gg[8] = {g0.x, g0.y, g0.z, g0.w, g1.x, g1.y, g1.z, g1.w};
  const float bb[8] = {b0.x, b0.y, b0.z, b0.w, b1.x, b1.y, b1.z, b1.w};
  float r[8];
#pragma unroll
  for (int j = 0; j < 8; ++j) r[j] = (vals[j] - mu) * rs * gg[j] + bb[j];
  uint2 po;
  po.x = pk4fp8(r[0], r[1], r[2], r[3]);
  po.y = pk4fp8(r[4], r[5], r[6], r[7]);
  *(uint2*)(y + orow * DIM + lane * 8) = po;
}

// ---------------- fp8 LDS staging via global_load_lds, source pre-swizzled (T2) ----------
// Tile rows are 128 B (BK=128 fp8). Physical 16B block pb of row stored at pb^(row&7).
template <int ROWS>
__device__ __forceinline__ void stage_lds8(const uint8_t* __restrict__ g, int ldKb,
                                           char* lds, int wave, int lane) {
  constexpr int RPW = ROWS / 4;  // rows per wave
  const int r0 = wave * RPW;
  const int ro = lane >> 3;
  const int pb = lane & 7;
  const uint8_t* src = g + (size_t)(r0 + ro) * (size_t)ldKb + ((pb ^ ro) << 4);
  char* dst = lds + r0 * 128;
#pragma unroll
  for (int c = 0; c < RPW; c += 8) {
    __builtin_amdgcn_global_load_lds((const as1void*)(src + (size_t)c * (size_t)ldKb),
                                     (as3void*)(dst + c * 128), 16, 0, 0);
  }
}

// fragment: 32 contiguous K-bytes for this lane = physical blocks {2g, 2g+1} ^ (row&7)
__device__ __forceinline__ v8i lds_frag8(const char* base, int row, int g) {
  const int ro = row & 7;
  const v4i lo = *(const v4i*)(base + row * 128 + (((2 * g) ^ ro) << 4));
  const v4i hi = *(const v4i*)(base + row * 128 + (((2 * g + 1) ^ ro) << 4));
  return __builtin_shufflevector(lo, hi, 0, 1, 2, 3, 4, 5, 6, 7);
}

#define MFMA_SC(a, b, c) \
  __builtin_amdgcn_mfma_scale_f32_16x16x128_f8f6f4((a), (b), (c), 0, 0, 0, 127, 0, 127)

// ---------------- 128x128 fp8 GEMM, C = A[M,K] * BT[N,K]^T ----------------
// MODE 0: out bf16 = acc + bias           (QKV)
// MODE 1: window-reverse; outf = resid + ls*(acc+bias)  (proj)
// MODE 2: outf = resid + ls*(acc+bias)    (fc2; resid may alias outf)
template <int MODE, int NT>
__global__ __launch_bounds__(256, 2) void k_gemm128(const uint8_t* __restrict__ A,
                                                    const uint8_t* __restrict__ BT,
                                                    const float* __restrict__ bias,
                                                    void* __restrict__ outp,
                                                    const float* __restrict__ resid,
                                                    const float* __restrict__ lsv, int K,
                                                    int ldOut) {
  __shared__ alignas(16) char As[128 * 128];
  __shared__ alignas(16) char Bs[128 * 128];
  const int nwg = gridDim.x;
  int bid = blockIdx.x;
  bid = (bid & 7) * (nwg >> 3) + (bid >> 3);  // bijective XCD swizzle (nwg % 8 == 0)
  const int bm = bid / NT, bn = bid % NT;
  const int tid = threadIdx.x;
  const int wave = tid >> 6, lane = tid & 63;
  const int wr = wave >> 1, wc = wave & 1;
  vf4 acc[4][4] = {};

  const uint8_t* Ab = A + (size_t)bm * 128 * K;
  const uint8_t* Bb = BT + (size_t)bn * 128 * K;
  const int cl = lane & 15, g = lane >> 4;
  const int arow = wr * 64 + cl;
  const int brow = wc * 64 + cl;
  const int nkt = K >> 7;

  for (int t = 0; t < nkt; ++t) {
    __syncthreads();
    stage_lds8<128>(Ab + t * 128, K, As, wave, lane);
    stage_lds8<128>(Bb + t * 128, K, Bs, wave, lane);
    __syncthreads();
    v8i af[4], bfr[4];
#pragma unroll
    for (int i = 0; i < 4; ++i) {
      af[i] = lds_frag8(As, arow + i * 16, g);
      bfr[i] = lds_frag8(Bs, brow + i * 16, g);
    }
#pragma unroll
    for (int mi = 0; mi < 4; ++mi)
#pragma unroll
      for (int ni = 0; ni < 4; ++ni)
        acc[mi][ni] = MFMA_SC(af[mi], bfr[ni], acc[mi][ni]);
  }

  const int rl = g << 2;
  const int rbase = bm * 128 + wr * 64;
  const int cbase = bn * 128 + wc * 64;
#pragma unroll
  for (int mi = 0; mi < 4; ++mi) {
#pragma unroll
    for (int j = 0; j < 4; ++j) {
      const int r = rbase + mi * 16 + rl + j;
      size_t orow;
      if (MODE == 1) {
        int m = r >> 6, t = r & 63;
        int b = m / 144, mm = m % 144;
        int wh = mm / 12, ww = mm % 12;
        int h = wh * 8 + (t >> 3), w = ww * 8 + (t & 7);
        orow = (size_t)((b * 96 + h) * 96 + w);
      } else {
        orow = (size_t)r;
      }
#pragma unroll
      for (int ni = 0; ni < 4; ++ni) {
        const int c = cbase + ni * 16 + cl;
        const float v = acc[mi][ni][j] + bias[c];
        if (MODE == 0) {
          ((__hip_bfloat16*)outp)[(size_t)r * ldOut + c] = __float2bfloat16(v);
        } else {
          float* of = (float*)outp;
          of[orow * DIM + c] = resid[orow * DIM + c] + lsv[c] * v;
        }
      }
    }
  }
}

// ---------------- GLU fp8 GEMM: dual-half (h, gate) with fused silu, fp8 h out -----------
__global__ __launch_bounds__(256, 2) void k_gemm_glu(const uint8_t* __restrict__ A,
                                                     const uint8_t* __restrict__ BT,
                                                     const float* __restrict__ bias,
                                                     uint8_t* __restrict__ hout) {
  __shared__ alignas(16) char As[128 * 128];
  __shared__ alignas(16) char B0s[64 * 128];
  __shared__ alignas(16) char B1s[64 * 128];
  const int K = DIM;
  const int nwg = gridDim.x;
  int bid = blockIdx.x;
  bid = (bid & 7) * (nwg >> 3) + (bid >> 3);  // bijective XCD swizzle
  const int bm = bid / 22, bn = bid % 22;
  const int tid = threadIdx.x;
  const int wave = tid >> 6, lane = tid & 63;
  const int wr = wave >> 1, wc = wave & 1;
  vf4 a0[4][2] = {}, a1[4][2] = {};

  const uint8_t* Ab = A + (size_t)bm * 128 * K;
  const uint8_t* Bb0 = BT + (size_t)(bn * 64) * K;
  const uint8_t* Bb1 = BT + (size_t)(INNERP + bn * 64) * K;
  const int cl = lane & 15, g = lane >> 4;
  const int arow = wr * 64 + cl;
  const int brow = wc * 32 + cl;

#pragma unroll
  for (int t = 0; t < 4; ++t) {
    __syncthreads();
    stage_lds8<128>(Ab + t * 128, K, As, wave, lane);
    stage_lds8<64>(Bb0 + t * 128, K, B0s, wave, lane);
    stage_lds8<64>(Bb1 + t * 128, K, B1s, wave, lane);
    __syncthreads();
    v8i af[4], b0f[2], b1f[2];
#pragma unroll
    for (int i = 0; i < 4; ++i) af[i] = lds_frag8(As, arow + i * 16, g);
#pragma unroll
    for (int i = 0; i < 2; ++i) {
      b0f[i] = lds_frag8(B0s, brow + i * 16, g);
      b1f[i] = lds_frag8(B1s, brow + i * 16, g);
    }
#pragma unroll
    for (int mi = 0; mi < 4; ++mi)
#pragma unroll
      for (int ni = 0; ni < 2; ++ni) {
        a0[mi][ni] = MFMA_SC(af[mi], b0f[ni], a0[mi][ni]);
        a1[mi][ni] = MFMA_SC(af[mi], b1f[ni], a1[mi][ni]);
      }
  }

  const int rl = g << 2;
  const int rbase = bm * 128 + wr * 64;
  const int cbase = bn * 64 + wc * 32;
#pragma unroll
  for (int mi = 0; mi < 4; ++mi)
#pragma unroll
    for (int j = 0; j < 4; ++j) {
      const int r = rbase + mi * 16 + rl + j;
#pragma unroll
      for (int ni = 0; ni < 2; ++ni) {
        const int c = cbase + ni * 16 + cl;
        const float a = a0[mi][ni][j] + bias[c];
        const float gv = a1[mi][ni][j] + bias[INNERP + c];
        const float sg = 1.0f / (1.0f + __expf(-gv));
        const float hv = a * gv * sg;
        hout[(size_t)r * INNERP + c] =
            (uint8_t)(__builtin_amdgcn_cvt_pk_fp8_f32(hv, hv, 0, false) & 0xff);
      }
    }
}

// ---------------- attention: MFMA, one wave per (window, head); fp8 o out ----------------
__global__ __launch_bounds__(256, 2) void k_attn_mfma(const __hip_bfloat16* __restrict__ qkv,
                                                      uint8_t* __restrict__ o) {
  __shared__ __hip_bfloat16 sm[4][6912];
  const int wave = threadIdx.x >> 6, lane = threadIdx.x & 63;
  const int task = blockIdx.x * 4 + wave;
  const int w = task >> 4, hd = task & 15;
  const int g = lane >> 4, c = lane & 15;
  __hip_bfloat16* smp = sm[wave];
  __hip_bfloat16* smv = smp + 4608;

  const __hip_bfloat16* base = qkv + (size_t)w * 64 * 1536 + hd * 32;

  vbf8 qf[4], kf[4];
#pragma unroll
  for (int i = 0; i < 4; ++i) {
    const __hip_bfloat16* qrow = base + (size_t)(i * 16 + c) * 1536 + g * 8;
    qf[i] = *(const vbf8*)qrow;
    kf[i] = *(const vbf8*)(qrow + 512);
  }

  {
    const __hip_bfloat16* vrow = base + (size_t)lane * 1536 + 1024;
    union {
      vbf8 v;
      ushort e[8];
    } uv[4];
#pragma unroll
    for (int i = 0; i < 4; ++i) uv[i].v = *(const vbf8*)(vrow + i * 8);
#pragma unroll
    for (int d = 0; d < 32; ++d)
      ((ushort*)smv)[d * 72 + lane] = uv[d >> 3].e[d & 7];
  }

  vf4 st[4][4];
#pragma unroll
  for (int iq = 0; iq < 4; ++iq)
#pragma unroll
    for (int it = 0; it < 4; ++it) {
      vf4 z = {};
      st[iq][it] = __builtin_amdgcn_mfma_f32_16x16x32_bf16(qf[iq], kf[it], z, 0, 0, 0);
    }

  float inv[4][4];
#pragma unroll
  for (int iq = 0; iq < 4; ++iq) {
#pragma unroll
    for (int j = 0; j < 4; ++j) {
      float m = fmaxf(fmaxf(st[iq][0][j], st[iq][1][j]), fmaxf(st[iq][2][j], st[iq][3][j]));
      m = fmaxf(m, __shfl_xor(m, 1));
      m = fmaxf(m, __shfl_xor(m, 2));
      m = fmaxf(m, __shfl_xor(m, 4));
      m = fmaxf(m, __shfl_xor(m, 8));
      float s = 0.f;
#pragma unroll
      for (int it = 0; it < 4; ++it) {
        const float e = __expf((st[iq][it][j] - m) * 0.17677669529663687f);
        st[iq][it][j] = e;
        s += e;
      }
      s += __shfl_xor(s, 1);
      s += __shfl_xor(s, 2);
      s += __shfl_xor(s, 4);
      s += __shfl_xor(s, 8);
      inv[iq][j] = 1.0f / s;
    }
  }

#pragma unroll
  for (int iq = 0; iq < 4; ++iq)
#pragma unroll
    for (int j = 0; j < 4; ++j) {
      const int q = iq * 16 + g * 4 + j;
#pragma unroll
      for (int it = 0; it < 4; ++it)
        smp[q * 72 + it * 16 + c] = __float2bfloat16(st[iq][it][j]);
    }

  vf4 ot[4][2] = {};
#pragma unroll
  for (int ks = 0; ks < 2; ++ks) {
    vbf8 pf[4], vfr[2];
#pragma unroll
    for (int iq = 0; iq < 4; ++iq)
      pf[iq] = *(const vbf8*)(smp + (iq * 16 + c) * 72 + ks * 32 + g * 8);
#pragma unroll
    for (int dt = 0; dt < 2; ++dt)
      vfr[dt] = *(const vbf8*)(smv + (dt * 16 + c) * 72 + ks * 32 + g * 8);
#pragma unroll
    for (int iq = 0; iq < 4; ++iq)
#pragma unroll
      for (int dt = 0; dt < 2; ++dt)
        ot[iq][dt] = __builtin_amdgcn_mfma_f32_16x16x32_bf16(pf[iq], vfr[dt], ot[iq][dt], 0, 0, 0);
  }

#pragma unroll
  for (int iq = 0; iq < 4; ++iq)
#pragma unroll
    for (int dt = 0; dt < 2; ++dt)
#pragma unroll
      for (int j = 0; j < 4; ++j) {
        const int q = iq * 16 + g * 4 + j;
        smp[q * 72 + dt * 16 + c] = __float2bfloat16(ot[iq][dt][j] * inv[iq][j]);
      }
  uint8_t* ob = o + (size_t)w * 64 * 512 + hd * 32;
#pragma unroll
  for (int i = 0; i < 4; ++i) {
    const int idx = i * 64 + lane;
    const int row = idx >> 2, chunk = idx & 3;
    union {
      vbf8 v;
      ushort e[8];
    } u;
    u.v = *(const vbf8*)(smp + row * 72 + chunk * 8);
    float f[8];
#pragma unroll
    for (int j = 0; j < 8; ++j) f[j] = __uint_as_float((unsigned)u.e[j] << 16);
    uint2 pv;
    pv.x = pk4fp8(f[0], f[1], f[2], f[3]);
    pv.y = pk4fp8(f[4], f[5], f[6], f[7]);
    *(uint2*)(ob + (size_t)row * 512 + chunk * 8) = pv;
  }
}

// ---------------- launch ----------------
extern "C" void kernel_launch(void* const* d_in, const int* in_sizes, int n_in, void* d_out,
                              int out_size, void* d_ws, size_t ws_size, hipStream_t stream) {
  const float* x = (const float*)d_in[0];
  const float* n1g = (const float*)d_in[1];
  const float* n1b = (const float*)d_in[2];
  const float* qkv_w = (const float*)d_in[3];
  const float* qkv_b = (const float*)d_in[4];
  const float* proj_w = (const float*)d_in[5];
  const float* proj_b = (const float*)d_in[6];
  const float* ls1 = (const float*)d_in[7];
  const float* n2g = (const float*)d_in[8];
  const float* n2b = (const float*)d_in[9];
  const float* glu_w = (const float*)d_in[10];
  const float* glu_b = (const float*)d_in[11];
  const float* fc2_w = (const float*)d_in[12];
  const float* fc2_b = (const float*)d_in[13];
  const float* ls2 = (const float*)d_in[14];

  if (ws_size < 268000000u) return;

  char* ws = (char*)d_ws;
  uint8_t* wTq = (uint8_t*)(ws + 0);                          // [1536][512] fp8
  uint8_t* wTp = (uint8_t*)(ws + 786432);                     // [512][512]
  uint8_t* wTg = (uint8_t*)(ws + 1048576);                    // [2816][512], padded
  uint8_t* wTf = (uint8_t*)(ws + 2490368);                    // [512][1408], padded
  float* gbias = (float*)(ws + 3211264);                      // [2816]
  uint8_t* ybuf = (uint8_t*)(ws + 3222528);                   // [73728][512] fp8 (y1/o/y2)
  __hip_bfloat16* qkvbuf = (__hip_bfloat16*)(ws + 40971264);  // [73728][1536] bf16
  uint8_t* hbuf = (uint8_t*)(ws + 40971264);                  // [73728][1408] fp8 (aliases qkv)
  float* x1 = (float*)d_out;

  hipMemsetAsync(wTg, 0, 1441792, stream);
  hipMemsetAsync(wTf, 0, 720896, stream);

  dim3 tb(32, 8);
  k_transpose<<<dim3(48, 16), tb, 0, stream>>>(qkv_w, wTq, 512, 1536, 512, 1 << 30);
  k_transpose<<<dim3(16, 16), tb, 0, stream>>>(proj_w, wTp, 512, 512, 512, 1 << 30);
  k_transpose<<<dim3(84, 16), tb, 0, stream>>>(glu_w, wTg, 512, 2688, 512, INNER);
  k_transpose<<<dim3(16, 42), tb, 0, stream>>>(fc2_w, wTf, 1344, 512, 1408, 1 << 30);
  k_padbias<<<11, 256, 0, stream>>>(glu_b, gbias);

  k_ln<true><<<18432, 256, 0, stream>>>(x, n1g, n1b, ybuf);
  k_gemm128<0, 12><<<6912, 256, 0, stream>>>(ybuf, wTq, qkv_b, qkvbuf, nullptr, nullptr, 512, 1536);
  k_attn_mfma<<<4608, 256, 0, stream>>>(qkvbuf, ybuf);
  k_gemm128<1, 4><<<2304, 256, 0, stream>>>(ybuf, wTp, proj_b, (void*)x1, x, ls1, 512, 512);
  k_ln<false><<<18432, 256, 0, stream>>>(x1, n2g, n2b, ybuf);
  k_gemm_glu<<<12672, 256, 0, stream>>>(ybuf, wTg, gbias, hbuf);
  k_gemm128<2, 4><<<2304, 256, 0, stream>>>(hbuf, wTf, fc2_b, d_out, x1, ls2, INNERP, 512);
}

// Round 6
// 571.477 us; speedup vs baseline: 1.6132x; 1.0112x over previous
//
#include <hip/hip_runtime.h>
#include <hip/hip_bf16.h>
#include <stdint.h>
#include <math.h>

#define DIM 512
#define INNER 1344
#define INNERP 1408

typedef __attribute__((ext_vector_type(8))) short vbf8;
typedef __attribute__((ext_vector_type(4))) float vf4;
typedef __attribute__((ext_vector_type(4))) int v4i;
typedef __attribute__((ext_vector_type(8))) int v8i;

typedef __attribute__((address_space(1))) void as1void;
typedef __attribute__((address_space(3))) void as3void;

union frag8 {
  v8i w;
  v4i h[2];
};

// ---- fp4 e2m1 quantizer: v already divided by scale, |v| clamps at 6 ----
__device__ __forceinline__ uint32_t quant4(float v) {
  uint32_t s = (__float_as_uint(v) >> 31) << 3;
  float a = fabsf(v);
  uint32_t m = (a > 0.25f) + (a > 0.75f) + (a > 1.25f) + (a > 1.75f) +
               (a > 2.5f) + (a > 3.5f) + (a > 5.0f);
  return s | m;
}
__device__ __forceinline__ uint32_t pack8fp4(const float* r) {
  uint32_t u = 0;
#pragma unroll
  for (int j = 0; j < 8; ++j) u |= quant4(r[j]) << (4 * j);
  return u;
}

#define MFMA4(a, b, c, sb) \
  __builtin_amdgcn_mfma_scale_f32_16x16x128_f8f6f4((a), (b), (c), 4, 4, 0, 127, 0, (sb))

// ---------------- weight transpose + MX-fp4 quantize ----------------
// WT4[n'][k/2] nibbles (low nibble = even k), Wsc[n'][k/32] e8m0 scales.
__global__ void k_transpose4(const float* __restrict__ Wsrc, uint8_t* __restrict__ WT,
                             uint8_t* __restrict__ Wsc, int K, int N, int ldB, int ldS,
                             int nsplit) {
  __shared__ float tile[32][33];
  const int tx = threadIdx.x, ty = threadIdx.y;
  const int n0 = blockIdx.x * 32, k0 = blockIdx.y * 32;
#pragma unroll
  for (int i = 0; i < 32; i += 8) {
    int k = k0 + ty + i, n = n0 + tx;
    if (k < K && n < N) tile[ty + i][tx] = Wsrc[(size_t)k * N + n];
  }
  __syncthreads();
  if (tx < 16) {
#pragma unroll
    for (int i = 0; i < 32; i += 8) {
      int n = n0 + ty + i;
      if (n >= N) continue;
      float v0 = tile[2 * tx][ty + i], v1 = tile[2 * tx + 1][ty + i];
      float m = fmaxf(fabsf(v0), fabsf(v1));
      m = fmaxf(m, __shfl_xor(m, 1));
      m = fmaxf(m, __shfl_xor(m, 2));
      m = fmaxf(m, __shfl_xor(m, 4));
      m = fmaxf(m, __shfl_xor(m, 8));
      uint8_t sbyte;
      float s;
      if (m < 1e-20f) {
        sbyte = 0;
        s = 0.0f;
      } else {
        int e = (int)ceilf(log2f(m * 0.166666672f));
        e = e < -126 ? -126 : (e > 126 ? 126 : e);
        sbyte = (uint8_t)(e + 127);
        s = exp2f((float)(-e));
      }
      int np = n + (n >= nsplit ? 64 : 0);
      WT[(size_t)np * ldB + (k0 >> 1) + tx] =
          (uint8_t)(quant4(v0 * s) | (quant4(v1 * s) << 4));
      if (tx == 0) Wsc[(size_t)np * ldS + (k0 >> 5)] = sbyte;
    }
  }
}

// ---------------- pad GLU bias into [2816] ----------------
__global__ void k_padbias(const float* __restrict__ b, float* __restrict__ o) {
  int c = blockIdx.x * 256 + threadIdx.x;
  if (c < INNER) o[c] = b[c];
  else if (c >= INNERP && c < INNERP + INNER) o[c] = b[c - 64];
  else if (c < 2816) o[c] = 0.0f;
}

// ---------------- LayerNorm (+ optional window partition) -> fp4 (scale 1.0) --------
template <bool PART, bool BF16IN>
__global__ __launch_bounds__(256) void k_ln(const void* __restrict__ xin,
                                            const float* __restrict__ gw,
                                            const float* __restrict__ bw,
                                            uint8_t* __restrict__ y) {
  const int wave = threadIdx.x >> 6, lane = threadIdx.x & 63;
  const int tok = blockIdx.x * 4 + wave;
  float vals[8];
  if (BF16IN) {
    const __hip_bfloat16* xr = (const __hip_bfloat16*)xin + (size_t)tok * DIM + lane * 8;
    union {
      vbf8 v;
      ushort e[8];
    } u;
    u.v = *(const vbf8*)xr;
#pragma unroll
    for (int j = 0; j < 8; ++j) vals[j] = __uint_as_float((unsigned)u.e[j] << 16);
  } else {
    const float* xr = (const float*)xin + (size_t)tok * DIM + lane * 8;
    const float4 v0 = *(const float4*)xr;
    const float4 v1 = *(const float4*)(xr + 4);
    vals[0] = v0.x; vals[1] = v0.y; vals[2] = v0.z; vals[3] = v0.w;
    vals[4] = v1.x; vals[5] = v1.y; vals[6] = v1.z; vals[7] = v1.w;
  }
  float s = 0.f, ss = 0.f;
#pragma unroll
  for (int j = 0; j < 8; ++j) {
    s += vals[j];
    ss += vals[j] * vals[j];
  }
#pragma unroll
  for (int off = 32; off > 0; off >>= 1) {
    s += __shfl_xor(s, off);
    ss += __shfl_xor(ss, off);
  }
  const float mu = s * (1.0f / DIM);
  const float rs = rsqrtf(ss * (1.0f / DIM) - mu * mu + 1e-6f);
  size_t orow;
  if (PART) {
    int b = tok / 9216, rem = tok % 9216;
    int h = rem / 96, w = rem % 96;
    orow = (size_t)(((b * 12 + (h >> 3)) * 12 + (w >> 3)) * 64 + (h & 7) * 8 + (w & 7));
  } else {
    orow = (size_t)tok;
  }
  const float4 g0 = *(const float4*)(gw + lane * 8);
  const float4 g1 = *(const float4*)(gw + lane * 8 + 4);
  const float4 b0 = *(const float4*)(bw + lane * 8);
  const float4 b1 = *(const float4*)(bw + lane * 8 + 4);
  const float gg[8] = {g0.x, g0.y, g0.z, g0.w, g1.x, g1.y, g1.z, g1.w};
  const float bb[8] = {b0.x, b0.y, b0.z, b0.w, b1.x, b1.y, b1.z, b1.w};
  float r[8];
#pragma unroll
  for (int j = 0; j < 8; ++j) r[j] = (vals[j] - mu) * rs * gg[j] + bb[j];
  *(uint32_t*)(y + orow * 256 + lane * 4) = pack8fp4(r);
}

// ---------------- fp4 LDS staging (64B rows), source pre-swizzled ----------------
template <int ROWS>
__device__ __forceinline__ void stage4(const uint8_t* __restrict__ gsrc, int RB, char* lds,
                                       int wave, int lane) {
  constexpr int RPW = ROWS / 4;
  const int r0 = wave * RPW;
  const int srw = lane >> 2, sbk = lane & 3;
  const uint8_t* src = gsrc + (size_t)(r0 + srw) * RB + ((sbk ^ (srw & 3)) << 4);
  char* dst = lds + r0 * 64;
#pragma unroll
  for (int c = 0; c < RPW; c += 16)
    __builtin_amdgcn_global_load_lds((const as1void*)(src + (size_t)c * RB),
                                     (as3void*)(dst + c * 64), 16, 0, 0);
}

// ---------------- 128x128 MX-fp4 GEMM, C = A[M,K] * BT[N,K]^T ----------------
// MODE 0: bf16 out = acc + bias                             (QKV)
// MODE 1: window-reverse; bf16 out = f32resid + ls*(acc+b)  (proj -> x1)
// MODE 2: f32 out = bf16resid + ls*(acc+b)                  (fc2 -> d_out)
template <int MODE, int NT>
__global__ __launch_bounds__(256, 3) void k_gemm4(const uint8_t* __restrict__ A4,
                                                  const uint8_t* __restrict__ B4,
                                                  const uint8_t* __restrict__ Bsc,
                                                  const float* __restrict__ bias,
                                                  void* __restrict__ outp,
                                                  const void* __restrict__ resid,
                                                  const float* __restrict__ lsv, const int K,
                                                  const int ldOut) {
  __shared__ alignas(16) char As[128 * 64];
  __shared__ alignas(16) char Bs[128 * 64];
  const int nwg = gridDim.x;
  int bid = blockIdx.x;
  bid = (bid & 7) * (nwg >> 3) + (bid >> 3);  // bijective XCD swizzle (nwg%8==0)
  const int bm = bid / NT, bn = bid % NT;
  const int tid = threadIdx.x, wave = tid >> 6, lane = tid & 63;
  const int wr = wave >> 1, wc = wave & 1;
  const int cl = lane & 15, g = lane >> 4;
  const int RB = K >> 1, KB = K >> 5, nkt = K >> 7;

  const uint8_t* Ab = A4 + (size_t)bm * 128 * RB;
  const uint8_t* Bb = B4 + (size_t)bn * 128 * RB;

  int aoff[4], boff[4];
  const uint8_t* bscp[4];
#pragma unroll
  for (int i = 0; i < 4; ++i) {
    int ra = wr * 64 + cl + i * 16;
    int rb = wc * 64 + cl + i * 16;
    aoff[i] = ra * 64 + ((g ^ (ra & 3)) << 4);
    boff[i] = rb * 64 + ((g ^ (rb & 3)) << 4);
    bscp[i] = Bsc + (size_t)(bn * 128 + rb) * KB + g;
  }

  frag8 afr[4], bfr[4];
#pragma unroll
  for (int i = 0; i < 4; ++i) {
    afr[i].w = (v8i){0, 0, 0, 0, 0, 0, 0, 0};
    bfr[i].w = (v8i){0, 0, 0, 0, 0, 0, 0, 0};
  }
  vf4 acc[4][4] = {};

  for (int t = 0; t < nkt; ++t) {
    __syncthreads();
    stage4<128>(Ab + t * 64, RB, As, wave, lane);
    stage4<128>(Bb + t * 64, RB, Bs, wave, lane);
    __syncthreads();
    int sb[4];
#pragma unroll
    for (int i = 0; i < 4; ++i) sb[i] = (int)bscp[i][t * 4];
#pragma unroll
    for (int i = 0; i < 4; ++i) {
      afr[i].h[0] = *(const v4i*)(As + aoff[i]);
      bfr[i].h[0] = *(const v4i*)(Bs + boff[i]);
    }
#pragma unroll
    for (int mi = 0; mi < 4; ++mi)
#pragma unroll
      for (int ni = 0; ni < 4; ++ni)
        acc[mi][ni] = MFMA4(afr[mi].w, bfr[ni].w, acc[mi][ni], sb[ni]);
  }

  const int rl = g << 2;
  const int rbase = bm * 128 + wr * 64;
  const int cbase = bn * 128 + wc * 64;
#pragma unroll
  for (int mi = 0; mi < 4; ++mi) {
#pragma unroll
    for (int j = 0; j < 4; ++j) {
      const int r = rbase + mi * 16 + rl + j;
      size_t orow;
      if (MODE == 1) {
        int m = r >> 6, t = r & 63;
        int b = m / 144, mm = m % 144;
        int wh = mm / 12, ww = mm % 12;
        int h = wh * 8 + (t >> 3), w = ww * 8 + (t & 7);
        orow = (size_t)((b * 96 + h) * 96 + w);
      } else {
        orow = (size_t)r;
      }
#pragma unroll
      for (int ni = 0; ni < 4; ++ni) {
        const int c = cbase + ni * 16 + cl;
        const float v = acc[mi][ni][j] + bias[c];
        if (MODE == 0) {
          ((__hip_bfloat16*)outp)[(size_t)r * ldOut + c] = __float2bfloat16(v);
        } else if (MODE == 1) {
          const float* rx = (const float*)resid;
          ((__hip_bfloat16*)outp)[orow * DIM + c] =
              __float2bfloat16(rx[orow * DIM + c] + lsv[c] * v);
        } else {
          const __hip_bfloat16* rx = (const __hip_bfloat16*)resid;
          ((float*)outp)[(size_t)r * DIM + c] =
              __bfloat162float(rx[(size_t)r * DIM + c]) + lsv[c] * v;
        }
      }
    }
  }
}

// ---------------- GLU MX-fp4 GEMM: dual-half + silu, fp4 h out (scale 1.0) ------------
__global__ __launch_bounds__(256, 3) void k_gemm_glu4(const uint8_t* __restrict__ A4,
                                                      const uint8_t* __restrict__ B4,
                                                      const uint8_t* __restrict__ Bsc,
                                                      const float* __restrict__ bias,
                                                      uint8_t* __restrict__ hout) {
  __shared__ alignas(16) char As[128 * 64];
  __shared__ alignas(16) char B0s[64 * 64];
  __shared__ alignas(16) char B1s[64 * 64];
  __shared__ float pane[4][64][17];
  const int K = DIM, RB = 256, KB = 16;
  const int nwg = gridDim.x;
  int bid = blockIdx.x;
  bid = (bid & 7) * (nwg >> 3) + (bid >> 3);
  const int bm = bid / 22, bn = bid % 22;
  const int tid = threadIdx.x, wave = tid >> 6, lane = tid & 63;
  const int wr = wave >> 1, wc = wave & 1;
  const int cl = lane & 15, g = lane >> 4;

  const uint8_t* Ab = A4 + (size_t)bm * 128 * RB;
  const uint8_t* Bb0 = B4 + (size_t)(bn * 64) * RB;
  const uint8_t* Bb1 = B4 + (size_t)(INNERP + bn * 64) * RB;

  int aoff[4], boff[2];
  const uint8_t* b0scp[2];
  const uint8_t* b1scp[2];
#pragma unroll
  for (int i = 0; i < 4; ++i) {
    int ra = wr * 64 + cl + i * 16;
    aoff[i] = ra * 64 + ((g ^ (ra & 3)) << 4);
  }
#pragma unroll
  for (int i = 0; i < 2; ++i) {
    int rb = wc * 32 + cl + i * 16;
    boff[i] = rb * 64 + ((g ^ (rb & 3)) << 4);
    b0scp[i] = Bsc + (size_t)(bn * 64 + rb) * KB + g;
    b1scp[i] = Bsc + (size_t)(INNERP + bn * 64 + rb) * KB + g;
  }

  frag8 afr[4], b0f[2], b1f[2];
#pragma unroll
  for (int i = 0; i < 4; ++i) afr[i].w = (v8i){0, 0, 0, 0, 0, 0, 0, 0};
#pragma unroll
  for (int i = 0; i < 2; ++i) {
    b0f[i].w = (v8i){0, 0, 0, 0, 0, 0, 0, 0};
    b1f[i].w = (v8i){0, 0, 0, 0, 0, 0, 0, 0};
  }
  vf4 a0[4][2] = {}, a1[4][2] = {};

#pragma unroll
  for (int t = 0; t < 4; ++t) {
    __syncthreads();
    stage4<128>(Ab + t * 64, RB, As, wave, lane);
    stage4<64>(Bb0 + t * 64, RB, B0s, wave, lane);
    stage4<64>(Bb1 + t * 64, RB, B1s, wave, lane);
    __syncthreads();
    int sb0[2], sb1[2];
#pragma unroll
    for (int i = 0; i < 2; ++i) {
      sb0[i] = (int)b0scp[i][t * 4];
      sb1[i] = (int)b1scp[i][t * 4];
    }
#pragma unroll
    for (int i = 0; i < 4; ++i) afr[i].h[0] = *(const v4i*)(As + aoff[i]);
#pragma unroll
    for (int i = 0; i < 2; ++i) {
      b0f[i].h[0] = *(const v4i*)(B0s + boff[i]);
      b1f[i].h[0] = *(const v4i*)(B1s + boff[i]);
    }
#pragma unroll
    for (int mi = 0; mi < 4; ++mi)
#pragma unroll
      for (int ni = 0; ni < 2; ++ni) {
        a0[mi][ni] = MFMA4(afr[mi].w, b0f[ni].w, a0[mi][ni], sb0[ni]);
        a1[mi][ni] = MFMA4(afr[mi].w, b1f[ni].w, a1[mi][ni], sb1[ni]);
      }
  }

  // epilogue: silu fuse, relayout through private pane, fp4 pack
  const int rbase = bm * 128 + wr * 64;
  const int cbase = bn * 64 + wc * 32;
#pragma unroll
  for (int ni = 0; ni < 2; ++ni) {
#pragma unroll
    for (int mi = 0; mi < 4; ++mi)
#pragma unroll
      for (int j = 0; j < 4; ++j) {
        const int c = cbase + ni * 16 + cl;
        const float a = a0[mi][ni][j] + bias[c];
        const float gv = a1[mi][ni][j] + bias[INNERP + c];
        const float sg = 1.0f / (1.0f + __expf(-gv));
        pane[wave][mi * 16 + g * 4 + j][cl] = a * gv * sg;
      }
    asm volatile("s_waitcnt lgkmcnt(0)" ::: "memory");
    __builtin_amdgcn_sched_barrier(0);
    {
      const float* pr = &pane[wave][lane][0];
      float v0[8], v1[8];
#pragma unroll
      for (int b = 0; b < 8; ++b) {
        v0[b] = pr[b];
        v1[b] = pr[8 + b];
      }
      uint8_t* hp = hout + (size_t)(rbase + lane) * 704 + ((cbase + ni * 16) >> 1);
      *(uint32_t*)hp = pack8fp4(v0);
      *(uint32_t*)(hp + 4) = pack8fp4(v1);
    }
    asm volatile("s_waitcnt lgkmcnt(0)" ::: "memory");
    __builtin_amdgcn_sched_barrier(0);
  }
}

// ---------------- attention: MFMA, one wave per (window, head); fp4 o out -------------
__global__ __launch_bounds__(256, 2) void k_attn_mfma(const __hip_bfloat16* __restrict__ qkv,
                                                      uint8_t* __restrict__ o) {
  __shared__ __hip_bfloat16 sm[4][6912];
  const int wave = threadIdx.x >> 6, lane = threadIdx.x & 63;
  const int task = blockIdx.x * 4 + wave;
  const int w = task >> 4, hd = task & 15;
  const int g = lane >> 4, c = lane & 15;
  __hip_bfloat16* smp = sm[wave];
  __hip_bfloat16* smv = smp + 4608;

  const __hip_bfloat16* base = qkv + (size_t)w * 64 * 1536 + hd * 32;

  vbf8 qf[4], kf[4];
#pragma unroll
  for (int i = 0; i < 4; ++i) {
    const __hip_bfloat16* qrow = base + (size_t)(i * 16 + c) * 1536 + g * 8;
    qf[i] = *(const vbf8*)qrow;
    kf[i] = *(const vbf8*)(qrow + 512);
  }

  {
    const __hip_bfloat16* vrow = base + (size_t)lane * 1536 + 1024;
    union {
      vbf8 v;
      ushort e[8];
    } uv[4];
#pragma unroll
    for (int i = 0; i < 4; ++i) uv[i].v = *(const vbf8*)(vrow + i * 8);
#pragma unroll
    for (int d = 0; d < 32; ++d)
      ((ushort*)smv)[d * 72 + lane] = uv[d >> 3].e[d & 7];
  }

  vf4 st[4][4];
#pragma unroll
  for (int iq = 0; iq < 4; ++iq)
#pragma unroll
    for (int it = 0; it < 4; ++it) {
      vf4 z = {};
      st[iq][it] = __builtin_amdgcn_mfma_f32_16x16x32_bf16(qf[iq], kf[it], z, 0, 0, 0);
    }

  float inv[4][4];
#pragma unroll
  for (int iq = 0; iq < 4; ++iq) {
#pragma unroll
    for (int j = 0; j < 4; ++j) {
      float m = fmaxf(fmaxf(st[iq][0][j], st[iq][1][j]), fmaxf(st[iq][2][j], st[iq][3][j]));
      m = fmaxf(m, __shfl_xor(m, 1));
      m = fmaxf(m, __shfl_xor(m, 2));
      m = fmaxf(m, __shfl_xor(m, 4));
      m = fmaxf(m, __shfl_xor(m, 8));
      float s = 0.f;
#pragma unroll
      for (int it = 0; it < 4; ++it) {
        const float e = __expf((st[iq][it][j] - m) * 0.17677669529663687f);
        st[iq][it][j] = e;
        s += e;
      }
      s += __shfl_xor(s, 1);
      s += __shfl_xor(s, 2);
      s += __shfl_xor(s, 4);
      s += __shfl_xor(s, 8);
      inv[iq][j] = 1.0f / s;
    }
  }

#pragma unroll
  for (int iq = 0; iq < 4; ++iq)
#pragma unroll
    for (int j = 0; j < 4; ++j) {
      const int q = iq * 16 + g * 4 + j;
#pragma unroll
      for (int it = 0; it < 4; ++it)
        smp[q * 72 + it * 16 + c] = __float2bfloat16(st[iq][it][j]);
    }

  vf4 ot[4][2] = {};
#pragma unroll
  for (int ks = 0; ks < 2; ++ks) {
    vbf8 pf[4], vfr[2];
#pragma unroll
    for (int iq = 0; iq < 4; ++iq)
      pf[iq] = *(const vbf8*)(smp + (iq * 16 + c) * 72 + ks * 32 + g * 8);
#pragma unroll
    for (int dt = 0; dt < 2; ++dt)
      vfr[dt] = *(const vbf8*)(smv + (dt * 16 + c) * 72 + ks * 32 + g * 8);
#pragma unroll
    for (int iq = 0; iq < 4; ++iq)
#pragma unroll
      for (int dt = 0; dt < 2; ++dt)
        ot[iq][dt] = __builtin_amdgcn_mfma_f32_16x16x32_bf16(pf[iq], vfr[dt], ot[iq][dt], 0, 0, 0);
  }

#pragma unroll
  for (int iq = 0; iq < 4; ++iq)
#pragma unroll
    for (int dt = 0; dt < 2; ++dt)
#pragma unroll
      for (int j = 0; j < 4; ++j) {
        const int q = iq * 16 + g * 4 + j;
        smp[q * 72 + dt * 16 + c] = __float2bfloat16(ot[iq][dt][j] * inv[iq][j]);
      }
  uint8_t* ob = o + (size_t)w * 64 * 256 + hd * 16;
#pragma unroll
  for (int i = 0; i < 4; ++i) {
    const int idx = i * 64 + lane;
    const int row = idx >> 2, chunk = idx & 3;
    union {
      vbf8 v;
      ushort e[8];
    } u;
    u.v = *(const vbf8*)(smp + row * 72 + chunk * 8);
    float f[8];
#pragma unroll
    for (int j = 0; j < 8; ++j) f[j] = __uint_as_float((unsigned)u.e[j] << 16);
    *(uint32_t*)(ob + (size_t)row * 256 + chunk * 4) = pack8fp4(f);
  }
}

// ---------------- launch ----------------
extern "C" void kernel_launch(void* const* d_in, const int* in_sizes, int n_in, void* d_out,
                              int out_size, void* d_ws, size_t ws_size, hipStream_t stream) {
  const float* x = (const float*)d_in[0];
  const float* n1g = (const float*)d_in[1];
  const float* n1b = (const float*)d_in[2];
  const float* qkv_w = (const float*)d_in[3];
  const float* qkv_b = (const float*)d_in[4];
  const float* proj_w = (const float*)d_in[5];
  const float* proj_b = (const float*)d_in[6];
  const float* ls1 = (const float*)d_in[7];
  const float* n2g = (const float*)d_in[8];
  const float* n2b = (const float*)d_in[9];
  const float* glu_w = (const float*)d_in[10];
  const float* glu_b = (const float*)d_in[11];
  const float* fc2_w = (const float*)d_in[12];
  const float* fc2_b = (const float*)d_in[13];
  const float* ls2 = (const float*)d_in[14];

  if (ws_size < 248000000u) return;

  char* ws = (char*)d_ws;
  uint8_t* wTq4 = (uint8_t*)(ws + 0);         // [1536][256]
  uint8_t* wTp4 = (uint8_t*)(ws + 393216);    // [512][256]
  uint8_t* wTg4 = (uint8_t*)(ws + 524288);    // [2816][256] padded
  uint8_t* wTf4 = (uint8_t*)(ws + 1245184);   // [512][704] padded
  uint8_t* sq = (uint8_t*)(ws + 1605632);     // [1536][16]
  uint8_t* sp = (uint8_t*)(ws + 1630208);     // [512][16]
  uint8_t* sg = (uint8_t*)(ws + 1638400);     // [2816][16]
  uint8_t* sf = (uint8_t*)(ws + 1683456);     // [512][44]
  float* gbias = (float*)(ws + 1705984);      // [2816]
  uint8_t* act4 = (uint8_t*)(ws + 2097152);   // [73728][256] fp4 (y1 -> o -> y2)
  char* big = ws + 20971520;                  // 226.5 MB region
  __hip_bfloat16* qkvbuf = (__hip_bfloat16*)big;        // [73728][1536] bf16
  uint8_t* h4 = (uint8_t*)big;                          // [73728][704] fp4 (after attn)
  __hip_bfloat16* x1b = (__hip_bfloat16*)(big + 69206016);  // [73728][512] bf16

  hipMemsetAsync(wTg4, 0, 720896, stream);
  hipMemsetAsync(wTf4, 0, 360448, stream);
  hipMemsetAsync(sg, 0, 45056, stream);
  hipMemsetAsync(sf, 0, 22528, stream);

  dim3 tb(32, 8);
  k_transpose4<<<dim3(48, 16), tb, 0, stream>>>(qkv_w, wTq4, sq, 512, 1536, 256, 16, 1 << 30);
  k_transpose4<<<dim3(16, 16), tb, 0, stream>>>(proj_w, wTp4, sp, 512, 512, 256, 16, 1 << 30);
  k_transpose4<<<dim3(84, 16), tb, 0, stream>>>(glu_w, wTg4, sg, 512, 2688, 256, 16, INNER);
  k_transpose4<<<dim3(16, 42), tb, 0, stream>>>(fc2_w, wTf4, sf, 1344, 512, 704, 44, 1 << 30);
  k_padbias<<<11, 256, 0, stream>>>(glu_b, gbias);

  k_ln<true, false><<<18432, 256, 0, stream>>>(x, n1g, n1b, act4);
  k_gemm4<0, 12><<<6912, 256, 0, stream>>>(act4, wTq4, sq, qkv_b, qkvbuf, nullptr, nullptr, 512, 1536);
  k_attn_mfma<<<4608, 256, 0, stream>>>(qkvbuf, act4);
  k_gemm4<1, 4><<<2304, 256, 0, stream>>>(act4, wTp4, sp, proj_b, (void*)x1b, x, ls1, 512, 512);
  k_ln<false, true><<<18432, 256, 0, stream>>>(x1b, n2g, n2b, act4);
  k_gemm_glu4<<<12672, 256, 0, stream>>>(act4, wTg4, sg, gbias, h4);
  k_gemm4<2, 4><<<2304, 256, 0, stream>>>(h4, wTf4, sf, fc2_b, d_out, x1b, ls2, 1408, 512);
}

// Round 7
// 570.100 us; speedup vs baseline: 1.6171x; 1.0024x over previous
//
#include <hip/hip_runtime.h>
#include <hip/hip_bf16.h>
#include <stdint.h>
#include <math.h>

#define DIM 512
#define INNER 1344
#define INNERP 1408

typedef __attribute__((ext_vector_type(8))) short vbf8;
typedef __attribute__((ext_vector_type(4))) float vf4;
typedef __attribute__((ext_vector_type(4))) int v4i;
typedef __attribute__((ext_vector_type(8))) int v8i;

typedef __attribute__((address_space(1))) void as1void;
typedef __attribute__((address_space(3))) void as3void;

union frag8 {
  v8i w;
  v4i h[2];
};

__device__ __forceinline__ unsigned pk4fp8(float a, float b, float c, float d) {
  int v = __builtin_amdgcn_cvt_pk_fp8_f32(a, b, 0, false);
  v = __builtin_amdgcn_cvt_pk_fp8_f32(c, d, v, true);
  return (unsigned)v;
}

// ---- fp4 e2m1 quantizer (setup-time only, weights) ----
__device__ __forceinline__ uint32_t quant4(float v) {
  uint32_t s = (__float_as_uint(v) >> 31) << 3;
  float a = fabsf(v);
  uint32_t m = (a > 0.25f) + (a > 0.75f) + (a > 1.25f) + (a > 1.75f) +
               (a > 2.5f) + (a > 3.5f) + (a > 5.0f);
  return s | m;
}

// A = fp8 (cbsz 0, scale 1.0), B = fp4 (blgp 4, per-block e8m0 scale)
#define MFMA_M(a, b, c, sb) \
  __builtin_amdgcn_mfma_scale_f32_16x16x128_f8f6f4((a), (b), (c), 0, 4, 0, 127, 0, (sb))

// ---------------- weight transpose + MX-fp4 quantize ----------------
__global__ void k_transpose4(const float* __restrict__ Wsrc, uint8_t* __restrict__ WT,
                             uint8_t* __restrict__ Wsc, int K, int N, int ldB, int ldS,
                             int nsplit) {
  __shared__ float tile[32][33];
  const int tx = threadIdx.x, ty = threadIdx.y;
  const int n0 = blockIdx.x * 32, k0 = blockIdx.y * 32;
#pragma unroll
  for (int i = 0; i < 32; i += 8) {
    int k = k0 + ty + i, n = n0 + tx;
    if (k < K && n < N) tile[ty + i][tx] = Wsrc[(size_t)k * N + n];
  }
  __syncthreads();
  if (tx < 16) {
#pragma unroll
    for (int i = 0; i < 32; i += 8) {
      int n = n0 + ty + i;
      if (n >= N) continue;
      float v0 = tile[2 * tx][ty + i], v1 = tile[2 * tx + 1][ty + i];
      float m = fmaxf(fabsf(v0), fabsf(v1));
      m = fmaxf(m, __shfl_xor(m, 1));
      m = fmaxf(m, __shfl_xor(m, 2));
      m = fmaxf(m, __shfl_xor(m, 4));
      m = fmaxf(m, __shfl_xor(m, 8));
      uint8_t sbyte;
      float s;
      if (m < 1e-20f) {
        sbyte = 0;
        s = 0.0f;
      } else {
        int e = (int)ceilf(log2f(m * 0.166666672f));
        e = e < -126 ? -126 : (e > 126 ? 126 : e);
        sbyte = (uint8_t)(e + 127);
        s = exp2f((float)(-e));
      }
      int np = n + (n >= nsplit ? 64 : 0);
      WT[(size_t)np * ldB + (k0 >> 1) + tx] =
          (uint8_t)(quant4(v0 * s) | (quant4(v1 * s) << 4));
      if (tx == 0) Wsc[(size_t)np * ldS + (k0 >> 5)] = sbyte;
    }
  }
}

// ---------------- pad GLU bias into [2816] ----------------
__global__ void k_padbias(const float* __restrict__ b, float* __restrict__ o) {
  int c = blockIdx.x * 256 + threadIdx.x;
  if (c < INNER) o[c] = b[c];
  else if (c >= INNERP && c < INNERP + INNER) o[c] = b[c - 64];
  else if (c < 2816) o[c] = 0.0f;
}

// ---------------- LayerNorm (+ optional window partition) -> fp8 ----------------
template <bool PART, bool BF16IN>
__global__ __launch_bounds__(256) void k_ln(const void* __restrict__ xin,
                                            const float* __restrict__ gw,
                                            const float* __restrict__ bw,
                                            uint8_t* __restrict__ y) {
  const int wave = threadIdx.x >> 6, lane = threadIdx.x & 63;
  const int tok = blockIdx.x * 4 + wave;
  float vals[8];
  if (BF16IN) {
    const __hip_bfloat16* xr = (const __hip_bfloat16*)xin + (size_t)tok * DIM + lane * 8;
    union {
      vbf8 v;
      ushort e[8];
    } u;
    u.v = *(const vbf8*)xr;
#pragma unroll
    for (int j = 0; j < 8; ++j) vals[j] = __uint_as_float((unsigned)u.e[j] << 16);
  } else {
    const float* xr = (const float*)xin + (size_t)tok * DIM + lane * 8;
    const float4 v0 = *(const float4*)xr;
    const float4 v1 = *(const float4*)(xr + 4);
    vals[0] = v0.x; vals[1] = v0.y; vals[2] = v0.z; vals[3] = v0.w;
    vals[4] = v1.x; vals[5] = v1.y; vals[6] = v1.z; vals[7] = v1.w;
  }
  float s = 0.f, ss = 0.f;
#pragma unroll
  for (int j = 0; j < 8; ++j) {
    s += vals[j];
    ss += vals[j] * vals[j];
  }
#pragma unroll
  for (int off = 32; off > 0; off >>= 1) {
    s += __shfl_xor(s, off);
    ss += __shfl_xor(ss, off);
  }
  const float mu = s * (1.0f / DIM);
  const float rs = rsqrtf(ss * (1.0f / DIM) - mu * mu + 1e-6f);
  size_t orow;
  if (PART) {
    int b = tok / 9216, rem = tok % 9216;
    int h = rem / 96, w = rem % 96;
    orow = (size_t)(((b * 12 + (h >> 3)) * 12 + (w >> 3)) * 64 + (h & 7) * 8 + (w & 7));
  } else {
    orow = (size_t)tok;
  }
  const float4 g0 = *(const float4*)(gw + lane * 8);
  const float4 g1 = *(const float4*)(gw + lane * 8 + 4);
  const float4 b0 = *(const float4*)(bw + lane * 8);
  const float4 b1 = *(const float4*)(bw + lane * 8 + 4);
  const float gg[8] = {g0.x, g0.y, g0.z, g0.w, g1.x, g1.y, g1.z, g1.w};
  const float bb[8] = {b0.x, b0.y, b0.z, b0.w, b1.x, b1.y, b1.z, b1.w};
  float r[8];
#pragma unroll
  for (int j = 0; j < 8; ++j) r[j] = (vals[j] - mu) * rs * gg[j] + bb[j];
  uint2 po;
  po.x = pk4fp8(r[0], r[1], r[2], r[3]);
  po.y = pk4fp8(r[4], r[5], r[6], r[7]);
  *(uint2*)(y + orow * DIM + lane * 8) = po;
}

// ---------------- fp8 A staging (128B rows), pre-swizzled src ----------------
template <int ROWS>
__device__ __forceinline__ void stage8(const uint8_t* __restrict__ g, int ldKb, char* lds,
                                       int wave, int lane) {
  constexpr int RPW = ROWS / 4;
  const int r0 = wave * RPW;
  const int ro = lane >> 3;
  const int pb = lane & 7;
  const uint8_t* src = g + (size_t)(r0 + ro) * (size_t)ldKb + ((pb ^ ro) << 4);
  char* dst = lds + r0 * 128;
#pragma unroll
  for (int c = 0; c < RPW; c += 8)
    __builtin_amdgcn_global_load_lds((const as1void*)(src + (size_t)c * (size_t)ldKb),
                                     (as3void*)(dst + c * 128), 16, 0, 0);
}
__device__ __forceinline__ v8i fragA8(const char* base, int row, int g) {
  const int ro = row & 7;
  const v4i lo = *(const v4i*)(base + row * 128 + (((2 * g) ^ ro) << 4));
  const v4i hi = *(const v4i*)(base + row * 128 + (((2 * g + 1) ^ ro) << 4));
  return __builtin_shufflevector(lo, hi, 0, 1, 2, 3, 4, 5, 6, 7);
}

// ---------------- fp4 B staging (64B rows), conflict-free swizzle ----------------
template <int ROWS>
__device__ __forceinline__ void stage4(const uint8_t* __restrict__ g, int ldKb, char* lds,
                                       int wave, int lane) {
  constexpr int RPW = ROWS / 4;
  const int r0 = wave * RPW;
  const int srw = lane >> 2, sbk = lane & 3;
  const int fsw = (srw + (srw >> 2)) & 3;
  const uint8_t* src = g + (size_t)(r0 + srw) * (size_t)ldKb + ((sbk ^ fsw) << 4);
  char* dst = lds + r0 * 64;
#pragma unroll
  for (int c = 0; c < RPW; c += 16)
    __builtin_amdgcn_global_load_lds((const as1void*)(src + (size_t)c * (size_t)ldKb),
                                     (as3void*)(dst + c * 64), 16, 0, 0);
}
__device__ __forceinline__ v4i fragB4(const char* base, int row, int g) {
  const int f = (row + (row >> 2)) & 3;
  return *(const v4i*)(base + row * 64 + ((g ^ f) << 4));
}

// ---------------- 128x128 mixed GEMM, C = A8[M,K] * B4[N,K]^T ----------------
// MODE 0: bf16 out = acc + bias                             (QKV)
// MODE 1: window-reverse; bf16 out = f32resid + ls*(acc+b)  (proj -> x1b)
// MODE 2: f32 out = bf16resid + ls*(acc+b)                  (fc2 -> d_out)
template <int MODE, int NT>
__global__ __launch_bounds__(256, 2) void k_gemm_m(const uint8_t* __restrict__ A8,
                                                   const uint8_t* __restrict__ B4,
                                                   const uint8_t* __restrict__ Bsc,
                                                   const float* __restrict__ bias,
                                                   void* __restrict__ outp,
                                                   const void* __restrict__ resid,
                                                   const float* __restrict__ lsv, const int K,
                                                   const int ldOut) {
  __shared__ alignas(16) char As[128 * 128];
  __shared__ alignas(16) char Bs[128 * 64];
  const int nwg = gridDim.x;
  int bid = blockIdx.x;
  bid = (bid & 7) * (nwg >> 3) + (bid >> 3);  // bijective XCD swizzle (nwg%8==0)
  const int bm = bid / NT, bn = bid % NT;
  const int tid = threadIdx.x, wave = tid >> 6, lane = tid & 63;
  const int wr = wave >> 1, wc = wave & 1;
  const int cl = lane & 15, g = lane >> 4;
  const int KB = K >> 5, nkt = K >> 7;

  const uint8_t* Ab = A8 + (size_t)bm * 128 * K;
  const uint8_t* Bb = B4 + (size_t)bn * 128 * (K >> 1);

  const uint8_t* bscp[4];
#pragma unroll
  for (int i = 0; i < 4; ++i)
    bscp[i] = Bsc + (size_t)(bn * 128 + wc * 64 + cl + i * 16) * KB + g;

  frag8 bfr[4];
#pragma unroll
  for (int i = 0; i < 4; ++i) bfr[i].w = (v8i){0, 0, 0, 0, 0, 0, 0, 0};
  vf4 acc[4][4] = {};

  for (int t = 0; t < nkt; ++t) {
    __syncthreads();
    stage8<128>(Ab + t * 128, K, As, wave, lane);
    stage4<128>(Bb + t * 64, K >> 1, Bs, wave, lane);
    __syncthreads();
    int sb[4];
#pragma unroll
    for (int i = 0; i < 4; ++i) sb[i] = (int)bscp[i][t * 4];
    v8i af[4];
#pragma unroll
    for (int i = 0; i < 4; ++i) {
      af[i] = fragA8(As, wr * 64 + cl + i * 16, g);
      bfr[i].h[0] = fragB4(Bs, wc * 64 + cl + i * 16, g);
    }
#pragma unroll
    for (int mi = 0; mi < 4; ++mi)
#pragma unroll
      for (int ni = 0; ni < 4; ++ni)
        acc[mi][ni] = MFMA_M(af[mi], bfr[ni].w, acc[mi][ni], sb[ni]);
  }

  const int rl = g << 2;
  const int rbase = bm * 128 + wr * 64;
  const int cbase = bn * 128 + wc * 64;
#pragma unroll
  for (int mi = 0; mi < 4; ++mi) {
#pragma unroll
    for (int j = 0; j < 4; ++j) {
      const int r = rbase + mi * 16 + rl + j;
      size_t orow;
      if (MODE == 1) {
        int m = r >> 6, t = r & 63;
        int b = m / 144, mm = m % 144;
        int wh = mm / 12, ww = mm % 12;
        int h = wh * 8 + (t >> 3), w = ww * 8 + (t & 7);
        orow = (size_t)((b * 96 + h) * 96 + w);
      } else {
        orow = (size_t)r;
      }
#pragma unroll
      for (int ni = 0; ni < 4; ++ni) {
        const int c = cbase + ni * 16 + cl;
        const float v = acc[mi][ni][j] + bias[c];
        if (MODE == 0) {
          ((__hip_bfloat16*)outp)[(size_t)r * ldOut + c] = __float2bfloat16(v);
        } else if (MODE == 1) {
          const float* rx = (const float*)resid;
          ((__hip_bfloat16*)outp)[orow * DIM + c] =
              __float2bfloat16(rx[orow * DIM + c] + lsv[c] * v);
        } else {
          const __hip_bfloat16* rx = (const __hip_bfloat16*)resid;
          ((float*)outp)[(size_t)r * DIM + c] =
              __bfloat162float(rx[(size_t)r * DIM + c]) + lsv[c] * v;
        }
      }
    }
  }
}

// ---------------- GLU mixed GEMM: dual-half + silu, fp8 h out ----------------
__global__ __launch_bounds__(256, 2) void k_gemm_glu_m(const uint8_t* __restrict__ A8,
                                                       const uint8_t* __restrict__ B4,
                                                       const uint8_t* __restrict__ Bsc,
                                                       const float* __restrict__ bias,
                                                       uint8_t* __restrict__ hout) {
  __shared__ alignas(16) char As[128 * 128];
  __shared__ alignas(16) char B0s[64 * 64];
  __shared__ alignas(16) char B1s[64 * 64];
  const int K = DIM, KB = 16;
  const int nwg = gridDim.x;
  int bid = blockIdx.x;
  bid = (bid & 7) * (nwg >> 3) + (bid >> 3);
  const int bm = bid / 22, bn = bid % 22;
  const int tid = threadIdx.x, wave = tid >> 6, lane = tid & 63;
  const int wr = wave >> 1, wc = wave & 1;
  const int cl = lane & 15, g = lane >> 4;

  const uint8_t* Ab = A8 + (size_t)bm * 128 * K;
  const uint8_t* Bb0 = B4 + (size_t)(bn * 64) * 256;
  const uint8_t* Bb1 = B4 + (size_t)(INNERP + bn * 64) * 256;

  const uint8_t* b0scp[2];
  const uint8_t* b1scp[2];
#pragma unroll
  for (int i = 0; i < 2; ++i) {
    int rb = wc * 32 + cl + i * 16;
    b0scp[i] = Bsc + (size_t)(bn * 64 + rb) * KB + g;
    b1scp[i] = Bsc + (size_t)(INNERP + bn * 64 + rb) * KB + g;
  }

  frag8 b0f[2], b1f[2];
#pragma unroll
  for (int i = 0; i < 2; ++i) {
    b0f[i].w = (v8i){0, 0, 0, 0, 0, 0, 0, 0};
    b1f[i].w = (v8i){0, 0, 0, 0, 0, 0, 0, 0};
  }
  vf4 a0[4][2] = {}, a1[4][2] = {};

#pragma unroll
  for (int t = 0; t < 4; ++t) {
    __syncthreads();
    stage8<128>(Ab + t * 128, K, As, wave, lane);
    stage4<64>(Bb0 + t * 64, 256, B0s, wave, lane);
    stage4<64>(Bb1 + t * 64, 256, B1s, wave, lane);
    __syncthreads();
    int sb0[2], sb1[2];
#pragma unroll
    for (int i = 0; i < 2; ++i) {
      sb0[i] = (int)b0scp[i][t * 4];
      sb1[i] = (int)b1scp[i][t * 4];
    }
    v8i af[4];
#pragma unroll
    for (int i = 0; i < 4; ++i) af[i] = fragA8(As, wr * 64 + cl + i * 16, g);
#pragma unroll
    for (int i = 0; i < 2; ++i) {
      b0f[i].h[0] = fragB4(B0s, wc * 32 + cl + i * 16, g);
      b1f[i].h[0] = fragB4(B1s, wc * 32 + cl + i * 16, g);
    }
#pragma unroll
    for (int mi = 0; mi < 4; ++mi)
#pragma unroll
      for (int ni = 0; ni < 2; ++ni) {
        a0[mi][ni] = MFMA_M(af[mi], b0f[ni].w, a0[mi][ni], sb0[ni]);
        a1[mi][ni] = MFMA_M(af[mi], b1f[ni].w, a1[mi][ni], sb1[ni]);
      }
  }

  const int rl = g << 2;
  const int rbase = bm * 128 + wr * 64;
  const int cbase = bn * 64 + wc * 32;
#pragma unroll
  for (int mi = 0; mi < 4; ++mi)
#pragma unroll
    for (int j = 0; j < 4; ++j) {
      const int r = rbase + mi * 16 + rl + j;
#pragma unroll
      for (int ni = 0; ni < 2; ++ni) {
        const int c = cbase + ni * 16 + cl;
        const float a = a0[mi][ni][j] + bias[c];
        const float gv = a1[mi][ni][j] + bias[INNERP + c];
        const float sg = 1.0f / (1.0f + __expf(-gv));
        const float hv = a * gv * sg;
        hout[(size_t)r * INNERP + c] =
            (uint8_t)(__builtin_amdgcn_cvt_pk_fp8_f32(hv, hv, 0, false) & 0xff);
      }
    }
}

// ---------------- attention: MFMA, one wave per (window, head); fp8 o out --------------
__global__ __launch_bounds__(256, 2) void k_attn_mfma(const __hip_bfloat16* __restrict__ qkv,
                                                      uint8_t* __restrict__ o) {
  __shared__ __hip_bfloat16 sm[4][6912];
  const int wave = threadIdx.x >> 6, lane = threadIdx.x & 63;
  const int task = blockIdx.x * 4 + wave;
  const int w = task >> 4, hd = task & 15;
  const int g = lane >> 4, c = lane & 15;
  __hip_bfloat16* smp = sm[wave];
  __hip_bfloat16* smv = smp + 4608;

  const __hip_bfloat16* base = qkv + (size_t)w * 64 * 1536 + hd * 32;

  vbf8 qf[4], kf[4];
#pragma unroll
  for (int i = 0; i < 4; ++i) {
    const __hip_bfloat16* qrow = base + (size_t)(i * 16 + c) * 1536 + g * 8;
    qf[i] = *(const vbf8*)qrow;
    kf[i] = *(const vbf8*)(qrow + 512);
  }

  {
    const __hip_bfloat16* vrow = base + (size_t)lane * 1536 + 1024;
    union {
      vbf8 v;
      ushort e[8];
    } uv[4];
#pragma unroll
    for (int i = 0; i < 4; ++i) uv[i].v = *(const vbf8*)(vrow + i * 8);
#pragma unroll
    for (int d = 0; d < 32; ++d)
      ((ushort*)smv)[d * 72 + lane] = uv[d >> 3].e[d & 7];
  }

  vf4 st[4][4];
#pragma unroll
  for (int iq = 0; iq < 4; ++iq)
#pragma unroll
    for (int it = 0; it < 4; ++it) {
      vf4 z = {};
      st[iq][it] = __builtin_amdgcn_mfma_f32_16x16x32_bf16(qf[iq], kf[it], z, 0, 0, 0);
    }

  float inv[4][4];
#pragma unroll
  for (int iq = 0; iq < 4; ++iq) {
#pragma unroll
    for (int j = 0; j < 4; ++j) {
      float m = fmaxf(fmaxf(st[iq][0][j], st[iq][1][j]), fmaxf(st[iq][2][j], st[iq][3][j]));
      m = fmaxf(m, __shfl_xor(m, 1));
      m = fmaxf(m, __shfl_xor(m, 2));
      m = fmaxf(m, __shfl_xor(m, 4));
      m = fmaxf(m, __shfl_xor(m, 8));
      float s = 0.f;
#pragma unroll
      for (int it = 0; it < 4; ++it) {
        const float e = __expf((st[iq][it][j] - m) * 0.17677669529663687f);
        st[iq][it][j] = e;
        s += e;
      }
      s += __shfl_xor(s, 1);
      s += __shfl_xor(s, 2);
      s += __shfl_xor(s, 4);
      s += __shfl_xor(s, 8);
      inv[iq][j] = 1.0f / s;
    }
  }

#pragma unroll
  for (int iq = 0; iq < 4; ++iq)
#pragma unroll
    for (int j = 0; j < 4; ++j) {
      const int q = iq * 16 + g * 4 + j;
#pragma unroll
      for (int it = 0; it < 4; ++it)
        smp[q * 72 + it * 16 + c] = __float2bfloat16(st[iq][it][j]);
    }

  vf4 ot[4][2] = {};
#pragma unroll
  for (int ks = 0; ks < 2; ++ks) {
    vbf8 pf[4], vfr[2];
#pragma unroll
    for (int iq = 0; iq < 4; ++iq)
      pf[iq] = *(const vbf8*)(smp + (iq * 16 + c) * 72 + ks * 32 + g * 8);
#pragma unroll
    for (int dt = 0; dt < 2; ++dt)
      vfr[dt] = *(const vbf8*)(smv + (dt * 16 + c) * 72 + ks * 32 + g * 8);
#pragma unroll
    for (int iq = 0; iq < 4; ++iq)
#pragma unroll
      for (int dt = 0; dt < 2; ++dt)
        ot[iq][dt] = __builtin_amdgcn_mfma_f32_16x16x32_bf16(pf[iq], vfr[dt], ot[iq][dt], 0, 0, 0);
  }

#pragma unroll
  for (int iq = 0; iq < 4; ++iq)
#pragma unroll
    for (int dt = 0; dt < 2; ++dt)
#pragma unroll
      for (int j = 0; j < 4; ++j) {
        const int q = iq * 16 + g * 4 + j;
        smp[q * 72 + dt * 16 + c] = __float2bfloat16(ot[iq][dt][j] * inv[iq][j]);
      }
  uint8_t* ob = o + (size_t)w * 64 * 512 + hd * 32;
#pragma unroll
  for (int i = 0; i < 4; ++i) {
    const int idx = i * 64 + lane;
    const int row = idx >> 2, chunk = idx & 3;
    union {
      vbf8 v;
      ushort e[8];
    } u;
    u.v = *(const vbf8*)(smp + row * 72 + chunk * 8);
    float f[8];
#pragma unroll
    for (int j = 0; j < 8; ++j) f[j] = __uint_as_float((unsigned)u.e[j] << 16);
    uint2 pv;
    pv.x = pk4fp8(f[0], f[1], f[2], f[3]);
    pv.y = pk4fp8(f[4], f[5], f[6], f[7]);
    *(uint2*)(ob + (size_t)row * 512 + chunk * 8) = pv;
  }
}

// ---------------- launch ----------------
extern "C" void kernel_launch(void* const* d_in, const int* in_sizes, int n_in, void* d_out,
                              int out_size, void* d_ws, size_t ws_size, hipStream_t stream) {
  const float* x = (const float*)d_in[0];
  const float* n1g = (const float*)d_in[1];
  const float* n1b = (const float*)d_in[2];
  const float* qkv_w = (const float*)d_in[3];
  const float* qkv_b = (const float*)d_in[4];
  const float* proj_w = (const float*)d_in[5];
  const float* proj_b = (const float*)d_in[6];
  const float* ls1 = (const float*)d_in[7];
  const float* n2g = (const float*)d_in[8];
  const float* n2b = (const float*)d_in[9];
  const float* glu_w = (const float*)d_in[10];
  const float* glu_b = (const float*)d_in[11];
  const float* fc2_w = (const float*)d_in[12];
  const float* fc2_b = (const float*)d_in[13];
  const float* ls2 = (const float*)d_in[14];

  if (ws_size < 268000000u) return;

  char* ws = (char*)d_ws;
  uint8_t* wTq4 = (uint8_t*)(ws + 0);         // [1536][256] fp4
  uint8_t* wTp4 = (uint8_t*)(ws + 393216);    // [512][256]
  uint8_t* wTg4 = (uint8_t*)(ws + 524288);    // [2816][256] padded
  uint8_t* wTf4 = (uint8_t*)(ws + 1245184);   // [512][704] padded
  uint8_t* sq = (uint8_t*)(ws + 1605632);     // [1536][16]
  uint8_t* sp = (uint8_t*)(ws + 1630208);     // [512][16]
  uint8_t* sg = (uint8_t*)(ws + 1638400);     // [2816][16]
  uint8_t* sf = (uint8_t*)(ws + 1683456);     // [512][44]
  float* gbias = (float*)(ws + 1705984);      // [2816]
  uint8_t* act8 = (uint8_t*)(ws + 2097152);   // [73728][512] fp8 (y1 -> o -> y2)
  char* big = ws + 39845888;
  __hip_bfloat16* qkvbuf = (__hip_bfloat16*)big;              // [73728][1536] bf16
  uint8_t* h8 = (uint8_t*)big;                                // [73728][1408] fp8 (alias)
  __hip_bfloat16* x1b = (__hip_bfloat16*)(big + 109051904);   // [73728][512] bf16

  hipMemsetAsync(wTg4, 0, 720896, stream);
  hipMemsetAsync(wTf4, 0, 360448, stream);
  hipMemsetAsync(sg, 0, 45056, stream);
  hipMemsetAsync(sf, 0, 22528, stream);

  dim3 tb(32, 8);
  k_transpose4<<<dim3(48, 16), tb, 0, stream>>>(qkv_w, wTq4, sq, 512, 1536, 256, 16, 1 << 30);
  k_transpose4<<<dim3(16, 16), tb, 0, stream>>>(proj_w, wTp4, sp, 512, 512, 256, 16, 1 << 30);
  k_transpose4<<<dim3(84, 16), tb, 0, stream>>>(glu_w, wTg4, sg, 512, 2688, 256, 16, INNER);
  k_transpose4<<<dim3(16, 42), tb, 0, stream>>>(fc2_w, wTf4, sf, 1344, 512, 704, 44, 1 << 30);
  k_padbias<<<11, 256, 0, stream>>>(glu_b, gbias);

  k_ln<true, false><<<18432, 256, 0, stream>>>(x, n1g, n1b, act8);
  k_gemm_m<0, 12><<<6912, 256, 0, stream>>>(act8, wTq4, sq, qkv_b, qkvbuf, nullptr, nullptr, 512, 1536);
  k_attn_mfma<<<4608, 256, 0, stream>>>(qkvbuf, act8);
  k_gemm_m<1, 4><<<2304, 256, 0, stream>>>(act8, wTp4, sp, proj_b, (void*)x1b, x, ls1, 512, 512);
  k_ln<false, true><<<18432, 256, 0, stream>>>(x1b, n2g, n2b, act8);
  k_gemm_glu_m<<<12672, 256, 0, stream>>>(act8, wTg4, sg, gbias, h8);
  k_gemm_m<2, 4><<<2304, 256, 0, stream>>>(h8, wTf4, sf, fc2_b, d_out, x1b, ls2, INNERP, 512);
}